// Round 8
// baseline (1322.039 us; speedup 1.0000x reference)
//
#include <hip/hip_runtime.h>
#include <hip/hip_fp16.h>
#include <math.h>

// Quantum circuit sim, 20 qubits, 4 layers, batch 16, purely-real f32 state.
// Element bit Ek <-> qubit q = 19-k. Same 7-pass math as the verified 257-us
// fp16 kernel (R A F L A* F* L*), now FUSED into ONE PERSISTENT KERNEL:
//   - 7*1024 = 7168 work tickets, p-major (pass, then batch, then tile)
//   - batch b is independent through the chain; pass p tile needs only
//     done[p-1][b]==64  -> soft per-batch boundaries instead of 6 global syncs
//   - block: grab ticket (atomic), spin on dep flag (thread0 + s_sleep,
//     bounded), run the byte-identical pass body, syncthreads (drains vmcnt),
//     threadfence (device release), atomicAdd done flag.
//   - Deadlock-free by induction for ANY occupancy: deps always have strictly
//     lower tickets and tickets are grabbed in monotone order.
//   - fp16 intermediates in two dedicated 32MB ws buffers (L3-resident);
//     d_out written only by the final pass (no aliasing with fp16 state).

#define NT 7168

__global__ void cs_zero_kernel(const float* __restrict__ theta,
                               float2* __restrict__ cs, int* __restrict__ ctrl) {
    int i = threadIdx.x;
    if (i < 80) {
        float s, c;
        sincosf(theta[i] * 0.5f, &s, &c);
        cs[i] = make_float2(c, s);
    }
    if (i < 112) ctrl[i] = 0;   // [0]=ticket, [1..96]=done flags
}

union H2U { __half2 h; unsigned u; };
__device__ __forceinline__ unsigned pk2(float a, float b) {
    H2U x; x.h = __float22half2_rn(make_float2(a, b)); return x.u;
}
__device__ __forceinline__ float2 upk2(unsigned u) {
    H2U x; x.u = u; return __half22float2(x.h);
}

// RY on fragment bit MASK with angle table TBL[Q]
#define RYT_(TBL, MASK, Q) { float2 _sc = (TBL)[(Q)]; float _c = _sc.x, _s = _sc.y; \
  _Pragma("unroll") for (int _m = 0; _m < 32; ++_m) if (!(_m & (MASK))) { \
    float _a = v[_m], _b = v[_m | (MASK)]; \
    v[_m] = _c*_a - _s*_b; v[_m | (MASK)] = _s*_a + _c*_b; } }

// CNOT: control mask CM, target mask TM, both in fragment
#define CX_(CM, TM) { _Pragma("unroll") for (int _m = 0; _m < 32; ++_m) \
  if ((_m & (CM)) && !(_m & (TM))) { float _t = v[_m]; v[_m] = v[_m|(TM)]; v[_m|(TM)] = _t; } }

// CNOT with control on a thread-index bit (COND), target mask TM in fragment
#define CXI_(COND, TM) { if (COND) { _Pragma("unroll") for (int _m = 0; _m < 32; ++_m) \
  if (!(_m & (TM))) { float _t = v[_m]; v[_m] = v[_m|(TM)]; v[_m|(TM)] = _t; } } }

__device__ __forceinline__ int mixR(int n) {
    return ((n >> 5) & 31) ^ ((n >> 10) & 1);
}
__device__ __forceinline__ int mixA(int n) {
    return ((n >> 5) & 31) ^ ((n >> 10) & 1) ^ (((n >> 11) & 1) << 3)
         ^ (((n >> 12) & 1) << 4) ^ (((n >> 13) & 1) << 4);
}
__device__ __forceinline__ int mixF(int n) {
    return ((n >> 5) & 31) ^ (((n >> 10) & 1) << 1) ^ (((n >> 11) & 1) << 2)
         ^ (((n >> 12) & 1) << 3) ^ (((n >> 13) & 1) << 4);
}
__device__ __forceinline__ int mixL(int n) {
    return ((n >> 5) & 31) ^ (((n >> 10) & 1) << 4) ^ (((n >> 11) & 1) << 2)
         ^ (((n >> 12) & 1) << 3) ^ (((n >> 13) & 1) << 4);
}

// ---------------- Pass R body: std(f32) -> B(fp16), RY on E13..E0 (layer 0) --
__device__ __forceinline__ void body_R(const float4* __restrict__ src,
    uint2* __restrict__ dst, const float2* __restrict__ cs,
    int blk, int t, float* lds)
{
    const float2* csl = cs;                       // layer 0
    int H = blk & 63, b = blk >> 6;
    int base = (b << 18) + (H << 12);
    float v[32];

#pragma unroll
    for (int i = 0; i < 8; ++i) {
        float4 w = src[base + (i << 8) + (((t >> 6) & 3) << 6) + (((t >> 8) & 1) << 11) + (t & 63)];
        v[i*4+0] = w.x; v[i*4+1] = w.y; v[i*4+2] = w.z; v[i*4+3] = w.w;
    }
    RYT_(csl, 1, 19); RYT_(csl, 2, 18); RYT_(csl, 4, 9); RYT_(csl, 8, 8); RYT_(csl, 16, 7);
    { int w1x = (t & 31) ^ ((t >> 5) & 1);
#pragma unroll
      for (int m = 0; m < 32; ++m) lds[(t << 5) | (m ^ w1x)] = v[m]; }
    __syncthreads();

    { int tp = (t & 31) | (((t >> 5) & 1) << 10) | (((t >> 6) & 7) << 11);
      int mt = mixR(tp);
#pragma unroll
      for (int f = 0; f < 32; ++f) { int fc = f << 5; v[f] = lds[(tp | fc) ^ mt ^ mixR(fc)]; }
      RYT_(csl, 1, 17); RYT_(csl, 2, 16); RYT_(csl, 4, 15); RYT_(csl, 8, 14); RYT_(csl, 16, 13);
#pragma unroll
      for (int f = 0; f < 32; ++f) { int fc = f << 5; lds[(tp | fc) ^ mt ^ mixR(fc)] = v[f]; } }
    __syncthreads();

    { int tp = ((t & 1) << 2) | (((t >> 1) & 1) << 3) | (((t >> 2) & 1) << 4)
             | (((t >> 3) & 1) << 5) | (((t >> 4) & 1) << 1) | (((t >> 5) & 1) << 0)
             | (((t >> 6) & 7) << 6);
      int mt = mixR(tp);
#pragma unroll
      for (int p = 0; p < 32; ++p) { int fc = p << 9; v[p] = lds[(tp | fc) ^ mt ^ mixR(fc)]; }
      RYT_(csl, 2, 12); RYT_(csl, 4, 11); RYT_(csl, 8, 10); RYT_(csl, 16, 6);
      int sb = base + (((t >> 6) & 7) << 6) + (t & 63);
#pragma unroll
      for (int j = 0; j < 8; ++j)
        dst[sb + (j << 9)] = make_uint2(pk2(v[4*j], v[4*j+1]), pk2(v[4*j+2], v[4*j+3])); }
}

// ---------------- Pass A body: M -> P (fp16) --------------------------------
__device__ __forceinline__ void body_A(const uint2* __restrict__ src,
    uint2* __restrict__ dst, const float2* __restrict__ cs,
    int layer, bool full, int blk, int t, float* lds)
{
    const float2* csl = cs + layer * 20;
    int G = blk & 63, b = blk >> 6;
    int Gperm = ((G >> 2) & 1) | (((G >> 1) & 1) << 1) | ((G & 1) << 2) | (((G >> 3) & 7) << 3);
    float v[32];

    { int lb = (b << 18) + (((t >> 6) & 7) << 9) + (Gperm << 3) + (t & 7);
      int rg = ((t >> 3) & 7) << 12;
#pragma unroll
      for (int i = 0; i < 8; ++i) {
        uint2 w = src[lb + ((i << 3) << 12) + rg];
        float2 lo = upk2(w.x), hi = upk2(w.y);
        v[i*4+0] = lo.x; v[i*4+1] = lo.y; v[i*4+2] = hi.x; v[i*4+3] = hi.y;
      } }
    RYT_(csl, 16, 0); RYT_(csl, 8, 1); RYT_(csl, 4, 2);
    if (full) { RYT_(csl, 2, 12); RYT_(csl, 1, 13); }
    { int w1x = (t & 31) ^ ((t >> 5) & 1) ^ (((t >> 6) & 1) << 3)
              ^ (((t >> 7) & 1) << 4) ^ (((t >> 8) & 1) << 4);
#pragma unroll
      for (int m = 0; m < 32; ++m) lds[(t << 5) | (m ^ w1x)] = v[m]; }
    __syncthreads();

    { int tp = (t & 3) | (((t >> 2) & 1) << 7) | (((t >> 3) & 1) << 11)
             | (((t >> 4) & 1) << 12) | (((t >> 5) & 1) << 13) | (((t >> 6) & 1) << 5)
             | (((t >> 7) & 1) << 6) | (((t >> 8) & 1) << 8);
      int mt = mixA(tp);
#pragma unroll
      for (int f = 0; f < 32; ++f) {
        int fc = ((f & 1) << 9) | (((f >> 1) & 1) << 10) | (((f >> 2) & 1) << 2)
               | (((f >> 3) & 1) << 3) | (((f >> 4) & 1) << 4);
        v[f] = lds[(tp | fc) ^ mt ^ mixA(fc)]; }
      RYT_(csl, 1, 4); RYT_(csl, 2, 3);
      CX_(16, 8); CX_(8, 4); CX_(4, 2); CX_(2, 1);
#pragma unroll
      for (int f = 0; f < 32; ++f) {
        int fc = ((f & 1) << 9) | (((f >> 1) & 1) << 10) | (((f >> 2) & 1) << 2)
               | (((f >> 3) & 1) << 3) | (((f >> 4) & 1) << 4);
        lds[(tp | fc) ^ mt ^ mixA(fc)] = v[f]; } }
    __syncthreads();

    { int tp = (t & 31) | (((t >> 5) & 1) << 9) | (((t >> 6) & 1) << 10)
             | (((t >> 7) & 1) << 11) | (((t >> 8) & 1) << 12);
      int mt = mixA(tp);
#pragma unroll
      for (int f = 0; f < 32; ++f) {
        int fc = ((f & 1) << 5) | (((f >> 1) & 1) << 6) | (((f >> 2) & 1) << 7)
               | (((f >> 3) & 1) << 13) | (((f >> 4) & 1) << 8);
        v[f] = lds[(tp | fc) ^ mt ^ mixA(fc)]; }
      RYT_(csl, 16, 5);
      if (full) { RYT_(csl, 8, 6); RYT_(csl, 4, 7); RYT_(csl, 2, 8); RYT_(csl, 1, 9); }
      CXI_((t >> 5) & 1, 16); CX_(16, 8); CX_(8, 4); CX_(4, 2); CX_(2, 1);
#pragma unroll
      for (int f = 0; f < 32; ++f) {
        int fc = ((f & 1) << 5) | (((f >> 1) & 1) << 6) | (((f >> 2) & 1) << 7)
               | (((f >> 3) & 1) << 13) | (((f >> 4) & 1) << 8);
        lds[(tp | fc) ^ mt ^ mixA(fc)] = v[f]; } }
    __syncthreads();

    { int tp = ((t & 1) << 8) | (((t >> 1) & 1) << 9) | (((t >> 2) & 1) << 10)
             | (((t >> 3) & 1) << 6) | (((t >> 4) & 1) << 7) | (((t >> 5) & 1) << 2)
             | (((t >> 6) & 1) << 5) | (((t >> 7) & 1) << 3) | (((t >> 8) & 1) << 4);
      int mt = mixA(tp);
#pragma unroll
      for (int p = 0; p < 32; ++p) {
        int fc = ((p & 1) << 0) | (((p >> 1) & 1) << 13) | (((p >> 2) & 1) << 1)
               | (((p >> 3) & 1) << 11) | (((p >> 4) & 1) << 12);
        v[p] = lds[(tp | fc) ^ mt ^ mixA(fc)]; }
      if (full) { RYT_(csl, 16, 10); RYT_(csl, 8, 11); }
      CXI_((t >> 6) & 1, 16); CX_(16, 8); CX_(8, 4); CX_(4, 1);
      int sb = (b << 18) + (G << 12) + t;
#pragma unroll
      for (int j = 0; j < 8; ++j)
        dst[sb + (j << 9)] = make_uint2(pk2(v[4*j], v[4*j+1]), pk2(v[4*j+2], v[4*j+3])); }
}

// ---------------- Pass F body: P -> Q (fp16) --------------------------------
__device__ __forceinline__ void body_F(const uint2* __restrict__ src,
    uint2* __restrict__ dst, const float2* __restrict__ cs,
    int layer, bool lowry, int blk, int t, float* lds)
{
    const float2* csl  = cs + layer * 20;
    const float2* csl2 = cs + (layer + 1) * 20;
    int W = blk & 63, b = blk >> 6;
    int Wp = (((W >> 4) & 1) << 3) | (((W >> 5) & 1) << 4) | (((W >> 3) & 1) << 6)
           | ((W & 1) << 9) | (((W >> 1) & 1) << 10) | (((W >> 2) & 1) << 11);
    float v[32];

    { int lb = (((b << 6) | ((t >> 3) & 63)) << 12) + (t & 7) + Wp;
#pragma unroll
      for (int i = 0; i < 8; ++i) {
        uint2 w = src[lb + ((i & 1) << 5) + (((i >> 1) & 1) << 7) + (((i >> 2) & 1) << 8)];
        float2 lo = upk2(w.x), hi = upk2(w.y);
        v[i*4+0] = lo.x; v[i*4+1] = lo.y; v[i*4+2] = hi.x; v[i*4+3] = hi.y;
      } }
    RYT_(csl2, 16, 0); RYT_(csl2, 8, 1); RYT_(csl2, 4, 2); RYT_(csl2, 2, 6);
    CX_(16, 8); CX_(8, 4);
    { int w1x = (t & 31) ^ (((t >> 5) & 1) << 1) ^ (((t >> 6) & 1) << 2)
              ^ (((t >> 7) & 1) << 3) ^ (((t >> 8) & 1) << 4);
#pragma unroll
      for (int m = 0; m < 32; ++m) lds[(t << 5) | (m ^ w1x)] = v[m]; }
    __syncthreads();

    { int tp = (t & 31) | (((t >> 5) & 1) << 8) | (((t >> 6) & 1) << 5)
             | (((t >> 7) & 1) << 6) | (((t >> 8) & 1) << 7);
      int mt = mixF(tp);
#pragma unroll
      for (int f = 0; f < 32; ++f) { int fc = f << 9; v[f] = lds[(tp | fc) ^ mt ^ mixF(fc)]; }
      if (lowry) { RYT_(csl, 16, 14); RYT_(csl, 8, 15); RYT_(csl, 4, 16); RYT_(csl, 2, 17); RYT_(csl, 1, 18); }
      CXI_(t & 1, 16); CX_(16, 8); CX_(8, 4); CX_(4, 2); CX_(2, 1);
#pragma unroll
      for (int f = 0; f < 32; ++f) { int fc = f << 9; lds[(tp | fc) ^ mt ^ mixF(fc)] = v[f]; } }
    __syncthreads();

    { int tp = ((t & 1) << 12) | (((t >> 1) & 1) << 13) | (((t >> 2) & 1) << 0)
             | (((t >> 3) & 1) << 9) | (((t >> 4) & 1) << 10) | (((t >> 5) & 1) << 11)
             | (((t >> 6) & 1) << 2) | (((t >> 7) & 1) << 3) | (((t >> 8) & 1) << 4);
      int mt = mixF(tp);
#pragma unroll
      for (int p = 0; p < 32; ++p) {
        int fc = ((p & 1) << 8) | (((p >> 1) & 1) << 1) | (((p >> 2) & 1) << 5)
               | (((p >> 3) & 1) << 6) | (((p >> 4) & 1) << 7);
        v[p] = lds[(tp | fc) ^ mt ^ mixF(fc)]; }
      if (lowry) { RYT_(csl, 1, 19); }
      CXI_((t >> 3) & 1, 1);
      RYT_(csl2, 16, 3); RYT_(csl2, 8, 4); RYT_(csl2, 4, 5);
      CXI_((t >> 6) & 1, 16); CX_(16, 8); CX_(8, 4); CX_(4, 2);
      int sb = (blk << 12) + t;
#pragma unroll
      for (int j = 0; j < 8; ++j)
        dst[sb + (j << 9)] = make_uint2(pk2(v[4*j], v[4*j+1]), pk2(v[4*j+2], v[4*j+3])); }
}

// ---------------- Pass L body: Q -> M (fp16) or std+abs (f32) ---------------
__device__ __forceinline__ void body_L(const uint2* __restrict__ src,
    float4* __restrict__ dstf, uint2* __restrict__ dsth,
    const float2* __restrict__ cs, int layer, bool fin, int blk, int t, float* lds)
{
    const float2* csl = cs + layer * 20;
    int H = blk & 63, b = blk >> 6;
    int Hp = (((H >> 3) & 7) << 6) | ((H & 7) << 9);
    float v[32];

    { int rb = (b << 6) | ((t >> 6) & 7);
      int lo = Hp + (t & 63);
#pragma unroll
      for (int i = 0; i < 8; ++i) {
        uint2 w = src[((rb | (i << 3)) << 12) + lo];
        float2 l2 = upk2(w.x), h2 = upk2(w.y);
        v[i*4+0] = l2.x; v[i*4+1] = l2.y; v[i*4+2] = h2.x; v[i*4+3] = h2.y;
      } }
    RYT_(csl, 1, 19); RYT_(csl, 4, 9); RYT_(csl, 8, 8); RYT_(csl, 16, 7);
    { int w1x = (t & 31) ^ (((t >> 5) & 1) << 4) ^ (((t >> 6) & 1) << 2)
              ^ (((t >> 7) & 1) << 3) ^ (((t >> 8) & 1) << 4);
#pragma unroll
      for (int m = 0; m < 32; ++m) lds[(t << 5) | (m ^ w1x)] = v[m]; }
    __syncthreads();

    { int tp = (t & 3) | (((t >> 2) & 1) << 7) | (((t >> 3) & 1) << 8)
             | (((t >> 4) & 1) << 9) | (((t >> 5) & 1) << 10) | (((t >> 6) & 1) << 5)
             | (((t >> 7) & 1) << 6) | (((t >> 8) & 1) << 11);
      int mt = mixL(tp);
#pragma unroll
      for (int f = 0; f < 32; ++f) {
        int fc = ((f & 1) << 12) | (((f >> 1) & 1) << 13) | (((f >> 2) & 1) << 2)
               | (((f >> 3) & 1) << 3) | (((f >> 4) & 1) << 4);
        v[f] = lds[(tp | fc) ^ mt ^ mixL(fc)]; }
      RYT_(csl, 2, 10); RYT_(csl, 1, 11);
      CXI_((t >> 1) & 1, 16); CX_(16, 8); CX_(8, 4); CX_(4, 2); CX_(2, 1);
#pragma unroll
      for (int f = 0; f < 32; ++f) {
        int fc = ((f & 1) << 12) | (((f >> 1) & 1) << 13) | (((f >> 2) & 1) << 2)
               | (((f >> 3) & 1) << 3) | (((f >> 4) & 1) << 4);
        lds[(tp | fc) ^ mt ^ mixL(fc)] = v[f]; } }
    __syncthreads();

    { int tp = (t & 31) | (((t >> 5) & 1) << 9) | (((t >> 6) & 1) << 8)
             | (((t >> 7) & 1) << 12) | (((t >> 8) & 1) << 13);
      int mt = mixL(tp);
#pragma unroll
      for (int f = 0; f < 32; ++f) {
        int fc = ((f & 1) << 10) | (((f >> 1) & 1) << 5) | (((f >> 2) & 1) << 6)
               | (((f >> 3) & 1) << 7) | (((f >> 4) & 1) << 11);
        v[f] = lds[(tp | fc) ^ mt ^ mixL(fc)]; }
      RYT_(csl, 16, 12); RYT_(csl, 8, 13); RYT_(csl, 4, 14); RYT_(csl, 2, 15); RYT_(csl, 1, 16);
      CXI_((t >> 7) & 1, 16); CX_(16, 8); CX_(8, 4); CX_(4, 2); CX_(2, 1);
#pragma unroll
      for (int f = 0; f < 32; ++f) {
        int fc = ((f & 1) << 10) | (((f >> 1) & 1) << 5) | (((f >> 2) & 1) << 6)
               | (((f >> 3) & 1) << 7) | (((f >> 4) & 1) << 11);
        lds[(tp | fc) ^ mt ^ mixL(fc)] = v[f]; } }
    __syncthreads();

    { int tp;
      if (!fin)
        tp = ((t & 1) << 2) | (((t >> 1) & 1) << 3) | (((t >> 2) & 1) << 4)
           | (((t >> 3) & 1) << 10) | (((t >> 4) & 1) << 5) | (((t >> 5) & 1) << 6)
           | (((t >> 6) & 1) << 1) | (((t >> 7) & 1) << 12) | (((t >> 8) & 1) << 13);
      else
        tp = ((t & 1) << 10) | (((t >> 1) & 1) << 5) | (((t >> 2) & 1) << 6)
           | (((t >> 3) & 1) << 12) | (((t >> 4) & 1) << 13) | (((t >> 5) & 1) << 2)
           | (((t >> 6) & 1) << 1) | (((t >> 7) & 1) << 3) | (((t >> 8) & 1) << 4);
      int mt = mixL(tp);
#pragma unroll
      for (int u = 0; u < 32; ++u) {
        int fc = ((u & 1) << 0) | (((u >> 1) & 1) << 8) | (((u >> 2) & 1) << 9)
               | (((u >> 3) & 1) << 7) | (((u >> 4) & 1) << 11);
        v[u] = lds[(tp | fc) ^ mt ^ mixL(fc)]; }
      RYT_(csl, 4, 17); RYT_(csl, 2, 18);
      { int e3 = fin ? (t & 1) : ((t >> 3) & 1);
        CXI_(e3, 4); }
      CX_(4, 2); CX_(2, 1);
      if (!fin) {
        int sb = (blk << 12) + (t & 7) + (((t >> 3) & 7) << 6)
               + (((t >> 7) & 3) << 9) + (((t >> 6) & 1) << 11);
#pragma unroll
        for (int g = 0; g < 8; ++g) {
          int bu = ((g >> 2) & 1) | (((g >> 1) & 1) << 1) | ((g & 1) << 2);
          dsth[sb + (g << 3)] = make_uint2(pk2(v[bu], v[bu | 8]), pk2(v[bu | 16], v[bu | 24]));
        }
      } else {
        int sb = (blk << 12) + ((t & 7) << 1) + (((t >> 3) & 7) << 6)
               + (((t >> 7) & 1) << 9) + (((t >> 8) & 1) << 10) + (((t >> 6) & 1) << 11);
#pragma unroll
        for (int g = 0; g < 8; ++g) {
          int bu = ((g & 1) << 2) | (((g >> 1) & 1) << 3) | (((g >> 2) & 1) << 4);
          dstf[sb + (g & 1) + (((g >> 1) & 1) << 4) + (((g >> 2) & 1) << 5)] =
            make_float4(fabsf(v[bu]), fabsf(v[bu | 1]), fabsf(v[bu | 2]), fabsf(v[bu | 3]));
        }
      } }
}

// ---------------- Persistent scheduler ----------------
__global__ __launch_bounds__(512, 4) void qsim(
    const float4* __restrict__ x, float4* __restrict__ outF,
    uint2* __restrict__ B0, uint2* __restrict__ B1,
    const float2* __restrict__ cs, int* __restrict__ ctrl)
{
    __shared__ float lds[16384];
    __shared__ int stk;
    int t = threadIdx.x;
    int* ticket = ctrl;
    int* done = ctrl + 1;   // done[p*16+b], p=0..5

    for (;;) {
        __syncthreads();                       // protect stk + lds reuse
        if (t == 0) stk = atomicAdd(ticket, 1);
        __syncthreads();
        int tk = stk;
        if (tk >= NT) break;                   // uniform exit
        int p = tk >> 10, r = tk & 1023, b = r >> 6, G = r & 63;
        int blk = (b << 6) | G;

        if (p > 0) {                           // wait for pass p-1, batch b
            if (t == 0) {
                int* f = done + (p - 1) * 16 + b;
                long spins = 0;
                while (__hip_atomic_load(f, __ATOMIC_RELAXED, __HIP_MEMORY_SCOPE_AGENT) < 64) {
                    __builtin_amdgcn_s_sleep(8);
                    if (++spins > (1L << 18)) break;   // bounded: bug -> wrong, not hang
                }
                __threadfence();               // acquire: invalidate L1/L2
            }
            __syncthreads();
        }

        if (p == 0)      body_R(x, B0, cs, blk, t, lds);
        else if (p == 1) body_A(B0, B1, cs, 0, false, blk, t, lds);
        else if (p == 2) body_F(B1, B0, cs, 0, false, blk, t, lds);
        else if (p == 3) body_L(B0, nullptr, B1, cs, 1, false, blk, t, lds);
        else if (p == 4) body_A(B1, B0, cs, 2, true, blk, t, lds);
        else if (p == 5) body_F(B0, B1, cs, 2, true, blk, t, lds);
        else             body_L(B1, outF, nullptr, cs, 3, true, blk, t, lds);

        __syncthreads();                       // drains vmcnt(0): stores in L2
        if (p < 6 && t == 0) {
            __threadfence();                   // release: writeback L2
            atomicAdd(done + p * 16 + b, 1);
        }
    }
}

extern "C" void kernel_launch(void* const* d_in, const int* in_sizes, int n_in,
                              void* d_out, int out_size, void* d_ws, size_t ws_size,
                              hipStream_t stream) {
    const float* x     = (const float*)d_in[0];   // (16, 2^20) f32, standard layout
    const float* theta = (const float*)d_in[1];   // (80,) f32
    float2* cs = (float2*)d_ws;                   // 80 (cos,sin) pairs @ +0
    int* ctrl  = (int*)((char*)d_ws + 1024);      // ticket + 96 done flags
    uint2* B0  = (uint2*)((char*)d_ws + 4096);            // 32 MB fp16 state
    uint2* B1  = (uint2*)((char*)d_ws + 4096 + (32u<<20)); // 32 MB fp16 state
    float4* outF = (float4*)d_out;

    cs_zero_kernel<<<1, 128, 0, stream>>>(theta, cs, ctrl);
    qsim<<<512, 512, 0, stream>>>((const float4*)x, outF, B0, B1, cs, ctrl);
}

// Round 9
// 1101.164 us; speedup vs baseline: 1.2006x; 1.2006x over previous
//
#include <hip/hip_runtime.h>
#include <hip/hip_fp16.h>
#include <math.h>

// Quantum circuit sim, 20 qubits, 4 layers, batch 16, purely-real f32 state.
// Element bit Ek <-> qubit q = 19-k. Same 7-pass math as the verified 257-us
// fp16 kernel (R A F L A* F* L*), FUSED into ONE PERSISTENT KERNEL:
//   - 7*1024 = 7168 work tickets, p-major (pass, then batch, then tile)
//   - batch b is independent through the chain; pass p tile needs only
//     done[p-1][b]==64  -> soft per-batch boundaries instead of 6 global syncs
//   - block: grab ticket (atomic), spin on dep flag (thread0 + s_sleep,
//     bounded), run the byte-identical pass body, syncthreads (drains vmcnt),
//     threadfence (device release), atomicAdd done flag.
//   - Deadlock-free by induction for ANY occupancy: deps always have strictly
//     lower tickets and tickets are grabbed in monotone order.
//   - fp16 intermediates in two dedicated 32MB ws buffers (L3-resident).
//   - __launch_bounds__(512, 2) on qsim: LDS (64KB+) caps occupancy at
//     2 blocks/CU anyway; min-waves=2 gives the allocator a 128-VGPR budget
//     so v[32] does NOT spill. R8 with (512,4) measured VGPR=64 and 2.0 GB
//     of scratch spill traffic -> 1253 us. Same bug+fix as R3->R4.

#define NT 7168

__global__ void cs_zero_kernel(const float* __restrict__ theta,
                               float2* __restrict__ cs, int* __restrict__ ctrl) {
    int i = threadIdx.x;
    if (i < 80) {
        float s, c;
        sincosf(theta[i] * 0.5f, &s, &c);
        cs[i] = make_float2(c, s);
    }
    if (i < 112) ctrl[i] = 0;   // [0]=ticket, [1..96]=done flags
}

union H2U { __half2 h; unsigned u; };
__device__ __forceinline__ unsigned pk2(float a, float b) {
    H2U x; x.h = __float22half2_rn(make_float2(a, b)); return x.u;
}
__device__ __forceinline__ float2 upk2(unsigned u) {
    H2U x; x.u = u; return __half22float2(x.h);
}

// RY on fragment bit MASK with angle table TBL[Q]
#define RYT_(TBL, MASK, Q) { float2 _sc = (TBL)[(Q)]; float _c = _sc.x, _s = _sc.y; \
  _Pragma("unroll") for (int _m = 0; _m < 32; ++_m) if (!(_m & (MASK))) { \
    float _a = v[_m], _b = v[_m | (MASK)]; \
    v[_m] = _c*_a - _s*_b; v[_m | (MASK)] = _s*_a + _c*_b; } }

// CNOT: control mask CM, target mask TM, both in fragment
#define CX_(CM, TM) { _Pragma("unroll") for (int _m = 0; _m < 32; ++_m) \
  if ((_m & (CM)) && !(_m & (TM))) { float _t = v[_m]; v[_m] = v[_m|(TM)]; v[_m|(TM)] = _t; } }

// CNOT with control on a thread-index bit (COND), target mask TM in fragment
#define CXI_(COND, TM) { if (COND) { _Pragma("unroll") for (int _m = 0; _m < 32; ++_m) \
  if (!(_m & (TM))) { float _t = v[_m]; v[_m] = v[_m|(TM)]; v[_m|(TM)] = _t; } } }

__device__ __forceinline__ int mixR(int n) {
    return ((n >> 5) & 31) ^ ((n >> 10) & 1);
}
__device__ __forceinline__ int mixA(int n) {
    return ((n >> 5) & 31) ^ ((n >> 10) & 1) ^ (((n >> 11) & 1) << 3)
         ^ (((n >> 12) & 1) << 4) ^ (((n >> 13) & 1) << 4);
}
__device__ __forceinline__ int mixF(int n) {
    return ((n >> 5) & 31) ^ (((n >> 10) & 1) << 1) ^ (((n >> 11) & 1) << 2)
         ^ (((n >> 12) & 1) << 3) ^ (((n >> 13) & 1) << 4);
}
__device__ __forceinline__ int mixL(int n) {
    return ((n >> 5) & 31) ^ (((n >> 10) & 1) << 4) ^ (((n >> 11) & 1) << 2)
         ^ (((n >> 12) & 1) << 3) ^ (((n >> 13) & 1) << 4);
}

// ---------------- Pass R body: std(f32) -> B(fp16), RY on E13..E0 (layer 0) --
__device__ __forceinline__ void body_R(const float4* __restrict__ src,
    uint2* __restrict__ dst, const float2* __restrict__ cs,
    int blk, int t, float* lds)
{
    const float2* csl = cs;                       // layer 0
    int H = blk & 63, b = blk >> 6;
    int base = (b << 18) + (H << 12);
    float v[32];

#pragma unroll
    for (int i = 0; i < 8; ++i) {
        float4 w = src[base + (i << 8) + (((t >> 6) & 3) << 6) + (((t >> 8) & 1) << 11) + (t & 63)];
        v[i*4+0] = w.x; v[i*4+1] = w.y; v[i*4+2] = w.z; v[i*4+3] = w.w;
    }
    RYT_(csl, 1, 19); RYT_(csl, 2, 18); RYT_(csl, 4, 9); RYT_(csl, 8, 8); RYT_(csl, 16, 7);
    { int w1x = (t & 31) ^ ((t >> 5) & 1);
#pragma unroll
      for (int m = 0; m < 32; ++m) lds[(t << 5) | (m ^ w1x)] = v[m]; }
    __syncthreads();

    { int tp = (t & 31) | (((t >> 5) & 1) << 10) | (((t >> 6) & 7) << 11);
      int mt = mixR(tp);
#pragma unroll
      for (int f = 0; f < 32; ++f) { int fc = f << 5; v[f] = lds[(tp | fc) ^ mt ^ mixR(fc)]; }
      RYT_(csl, 1, 17); RYT_(csl, 2, 16); RYT_(csl, 4, 15); RYT_(csl, 8, 14); RYT_(csl, 16, 13);
#pragma unroll
      for (int f = 0; f < 32; ++f) { int fc = f << 5; lds[(tp | fc) ^ mt ^ mixR(fc)] = v[f]; } }
    __syncthreads();

    { int tp = ((t & 1) << 2) | (((t >> 1) & 1) << 3) | (((t >> 2) & 1) << 4)
             | (((t >> 3) & 1) << 5) | (((t >> 4) & 1) << 1) | (((t >> 5) & 1) << 0)
             | (((t >> 6) & 7) << 6);
      int mt = mixR(tp);
#pragma unroll
      for (int p = 0; p < 32; ++p) { int fc = p << 9; v[p] = lds[(tp | fc) ^ mt ^ mixR(fc)]; }
      RYT_(csl, 2, 12); RYT_(csl, 4, 11); RYT_(csl, 8, 10); RYT_(csl, 16, 6);
      int sb = base + (((t >> 6) & 7) << 6) + (t & 63);
#pragma unroll
      for (int j = 0; j < 8; ++j)
        dst[sb + (j << 9)] = make_uint2(pk2(v[4*j], v[4*j+1]), pk2(v[4*j+2], v[4*j+3])); }
}

// ---------------- Pass A body: M -> P (fp16) --------------------------------
__device__ __forceinline__ void body_A(const uint2* __restrict__ src,
    uint2* __restrict__ dst, const float2* __restrict__ cs,
    int layer, bool full, int blk, int t, float* lds)
{
    const float2* csl = cs + layer * 20;
    int G = blk & 63, b = blk >> 6;
    int Gperm = ((G >> 2) & 1) | (((G >> 1) & 1) << 1) | ((G & 1) << 2) | (((G >> 3) & 7) << 3);
    float v[32];

    { int lb = (b << 18) + (((t >> 6) & 7) << 9) + (Gperm << 3) + (t & 7);
      int rg = ((t >> 3) & 7) << 12;
#pragma unroll
      for (int i = 0; i < 8; ++i) {
        uint2 w = src[lb + ((i << 3) << 12) + rg];
        float2 lo = upk2(w.x), hi = upk2(w.y);
        v[i*4+0] = lo.x; v[i*4+1] = lo.y; v[i*4+2] = hi.x; v[i*4+3] = hi.y;
      } }
    RYT_(csl, 16, 0); RYT_(csl, 8, 1); RYT_(csl, 4, 2);
    if (full) { RYT_(csl, 2, 12); RYT_(csl, 1, 13); }
    { int w1x = (t & 31) ^ ((t >> 5) & 1) ^ (((t >> 6) & 1) << 3)
              ^ (((t >> 7) & 1) << 4) ^ (((t >> 8) & 1) << 4);
#pragma unroll
      for (int m = 0; m < 32; ++m) lds[(t << 5) | (m ^ w1x)] = v[m]; }
    __syncthreads();

    { int tp = (t & 3) | (((t >> 2) & 1) << 7) | (((t >> 3) & 1) << 11)
             | (((t >> 4) & 1) << 12) | (((t >> 5) & 1) << 13) | (((t >> 6) & 1) << 5)
             | (((t >> 7) & 1) << 6) | (((t >> 8) & 1) << 8);
      int mt = mixA(tp);
#pragma unroll
      for (int f = 0; f < 32; ++f) {
        int fc = ((f & 1) << 9) | (((f >> 1) & 1) << 10) | (((f >> 2) & 1) << 2)
               | (((f >> 3) & 1) << 3) | (((f >> 4) & 1) << 4);
        v[f] = lds[(tp | fc) ^ mt ^ mixA(fc)]; }
      RYT_(csl, 1, 4); RYT_(csl, 2, 3);
      CX_(16, 8); CX_(8, 4); CX_(4, 2); CX_(2, 1);
#pragma unroll
      for (int f = 0; f < 32; ++f) {
        int fc = ((f & 1) << 9) | (((f >> 1) & 1) << 10) | (((f >> 2) & 1) << 2)
               | (((f >> 3) & 1) << 3) | (((f >> 4) & 1) << 4);
        lds[(tp | fc) ^ mt ^ mixA(fc)] = v[f]; } }
    __syncthreads();

    { int tp = (t & 31) | (((t >> 5) & 1) << 9) | (((t >> 6) & 1) << 10)
             | (((t >> 7) & 1) << 11) | (((t >> 8) & 1) << 12);
      int mt = mixA(tp);
#pragma unroll
      for (int f = 0; f < 32; ++f) {
        int fc = ((f & 1) << 5) | (((f >> 1) & 1) << 6) | (((f >> 2) & 1) << 7)
               | (((f >> 3) & 1) << 13) | (((f >> 4) & 1) << 8);
        v[f] = lds[(tp | fc) ^ mt ^ mixA(fc)]; }
      RYT_(csl, 16, 5);
      if (full) { RYT_(csl, 8, 6); RYT_(csl, 4, 7); RYT_(csl, 2, 8); RYT_(csl, 1, 9); }
      CXI_((t >> 5) & 1, 16); CX_(16, 8); CX_(8, 4); CX_(4, 2); CX_(2, 1);
#pragma unroll
      for (int f = 0; f < 32; ++f) {
        int fc = ((f & 1) << 5) | (((f >> 1) & 1) << 6) | (((f >> 2) & 1) << 7)
               | (((f >> 3) & 1) << 13) | (((f >> 4) & 1) << 8);
        lds[(tp | fc) ^ mt ^ mixA(fc)] = v[f]; } }
    __syncthreads();

    { int tp = ((t & 1) << 8) | (((t >> 1) & 1) << 9) | (((t >> 2) & 1) << 10)
             | (((t >> 3) & 1) << 6) | (((t >> 4) & 1) << 7) | (((t >> 5) & 1) << 2)
             | (((t >> 6) & 1) << 5) | (((t >> 7) & 1) << 3) | (((t >> 8) & 1) << 4);
      int mt = mixA(tp);
#pragma unroll
      for (int p = 0; p < 32; ++p) {
        int fc = ((p & 1) << 0) | (((p >> 1) & 1) << 13) | (((p >> 2) & 1) << 1)
               | (((p >> 3) & 1) << 11) | (((p >> 4) & 1) << 12);
        v[p] = lds[(tp | fc) ^ mt ^ mixA(fc)]; }
      if (full) { RYT_(csl, 16, 10); RYT_(csl, 8, 11); }
      CXI_((t >> 6) & 1, 16); CX_(16, 8); CX_(8, 4); CX_(4, 1);
      int sb = (b << 18) + (G << 12) + t;
#pragma unroll
      for (int j = 0; j < 8; ++j)
        dst[sb + (j << 9)] = make_uint2(pk2(v[4*j], v[4*j+1]), pk2(v[4*j+2], v[4*j+3])); }
}

// ---------------- Pass F body: P -> Q (fp16) --------------------------------
__device__ __forceinline__ void body_F(const uint2* __restrict__ src,
    uint2* __restrict__ dst, const float2* __restrict__ cs,
    int layer, bool lowry, int blk, int t, float* lds)
{
    const float2* csl  = cs + layer * 20;
    const float2* csl2 = cs + (layer + 1) * 20;
    int W = blk & 63, b = blk >> 6;
    int Wp = (((W >> 4) & 1) << 3) | (((W >> 5) & 1) << 4) | (((W >> 3) & 1) << 6)
           | ((W & 1) << 9) | (((W >> 1) & 1) << 10) | (((W >> 2) & 1) << 11);
    float v[32];

    { int lb = (((b << 6) | ((t >> 3) & 63)) << 12) + (t & 7) + Wp;
#pragma unroll
      for (int i = 0; i < 8; ++i) {
        uint2 w = src[lb + ((i & 1) << 5) + (((i >> 1) & 1) << 7) + (((i >> 2) & 1) << 8)];
        float2 lo = upk2(w.x), hi = upk2(w.y);
        v[i*4+0] = lo.x; v[i*4+1] = lo.y; v[i*4+2] = hi.x; v[i*4+3] = hi.y;
      } }
    RYT_(csl2, 16, 0); RYT_(csl2, 8, 1); RYT_(csl2, 4, 2); RYT_(csl2, 2, 6);
    CX_(16, 8); CX_(8, 4);
    { int w1x = (t & 31) ^ (((t >> 5) & 1) << 1) ^ (((t >> 6) & 1) << 2)
              ^ (((t >> 7) & 1) << 3) ^ (((t >> 8) & 1) << 4);
#pragma unroll
      for (int m = 0; m < 32; ++m) lds[(t << 5) | (m ^ w1x)] = v[m]; }
    __syncthreads();

    { int tp = (t & 31) | (((t >> 5) & 1) << 8) | (((t >> 6) & 1) << 5)
             | (((t >> 7) & 1) << 6) | (((t >> 8) & 1) << 7);
      int mt = mixF(tp);
#pragma unroll
      for (int f = 0; f < 32; ++f) { int fc = f << 9; v[f] = lds[(tp | fc) ^ mt ^ mixF(fc)]; }
      if (lowry) { RYT_(csl, 16, 14); RYT_(csl, 8, 15); RYT_(csl, 4, 16); RYT_(csl, 2, 17); RYT_(csl, 1, 18); }
      CXI_(t & 1, 16); CX_(16, 8); CX_(8, 4); CX_(4, 2); CX_(2, 1);
#pragma unroll
      for (int f = 0; f < 32; ++f) { int fc = f << 9; lds[(tp | fc) ^ mt ^ mixF(fc)] = v[f]; } }
    __syncthreads();

    { int tp = ((t & 1) << 12) | (((t >> 1) & 1) << 13) | (((t >> 2) & 1) << 0)
             | (((t >> 3) & 1) << 9) | (((t >> 4) & 1) << 10) | (((t >> 5) & 1) << 11)
             | (((t >> 6) & 1) << 2) | (((t >> 7) & 1) << 3) | (((t >> 8) & 1) << 4);
      int mt = mixF(tp);
#pragma unroll
      for (int p = 0; p < 32; ++p) {
        int fc = ((p & 1) << 8) | (((p >> 1) & 1) << 1) | (((p >> 2) & 1) << 5)
               | (((p >> 3) & 1) << 6) | (((p >> 4) & 1) << 7);
        v[p] = lds[(tp | fc) ^ mt ^ mixF(fc)]; }
      if (lowry) { RYT_(csl, 1, 19); }
      CXI_((t >> 3) & 1, 1);
      RYT_(csl2, 16, 3); RYT_(csl2, 8, 4); RYT_(csl2, 4, 5);
      CXI_((t >> 6) & 1, 16); CX_(16, 8); CX_(8, 4); CX_(4, 2);
      int sb = (blk << 12) + t;
#pragma unroll
      for (int j = 0; j < 8; ++j)
        dst[sb + (j << 9)] = make_uint2(pk2(v[4*j], v[4*j+1]), pk2(v[4*j+2], v[4*j+3])); }
}

// ---------------- Pass L body: Q -> M (fp16) or std+abs (f32) ---------------
__device__ __forceinline__ void body_L(const uint2* __restrict__ src,
    float4* __restrict__ dstf, uint2* __restrict__ dsth,
    const float2* __restrict__ cs, int layer, bool fin, int blk, int t, float* lds)
{
    const float2* csl = cs + layer * 20;
    int H = blk & 63, b = blk >> 6;
    int Hp = (((H >> 3) & 7) << 6) | ((H & 7) << 9);
    float v[32];

    { int rb = (b << 6) | ((t >> 6) & 7);
      int lo = Hp + (t & 63);
#pragma unroll
      for (int i = 0; i < 8; ++i) {
        uint2 w = src[((rb | (i << 3)) << 12) + lo];
        float2 l2 = upk2(w.x), h2 = upk2(w.y);
        v[i*4+0] = l2.x; v[i*4+1] = l2.y; v[i*4+2] = h2.x; v[i*4+3] = h2.y;
      } }
    RYT_(csl, 1, 19); RYT_(csl, 4, 9); RYT_(csl, 8, 8); RYT_(csl, 16, 7);
    { int w1x = (t & 31) ^ (((t >> 5) & 1) << 4) ^ (((t >> 6) & 1) << 2)
              ^ (((t >> 7) & 1) << 3) ^ (((t >> 8) & 1) << 4);
#pragma unroll
      for (int m = 0; m < 32; ++m) lds[(t << 5) | (m ^ w1x)] = v[m]; }
    __syncthreads();

    { int tp = (t & 3) | (((t >> 2) & 1) << 7) | (((t >> 3) & 1) << 8)
             | (((t >> 4) & 1) << 9) | (((t >> 5) & 1) << 10) | (((t >> 6) & 1) << 5)
             | (((t >> 7) & 1) << 6) | (((t >> 8) & 1) << 11);
      int mt = mixL(tp);
#pragma unroll
      for (int f = 0; f < 32; ++f) {
        int fc = ((f & 1) << 12) | (((f >> 1) & 1) << 13) | (((f >> 2) & 1) << 2)
               | (((f >> 3) & 1) << 3) | (((f >> 4) & 1) << 4);
        v[f] = lds[(tp | fc) ^ mt ^ mixL(fc)]; }
      RYT_(csl, 2, 10); RYT_(csl, 1, 11);
      CXI_((t >> 1) & 1, 16); CX_(16, 8); CX_(8, 4); CX_(4, 2); CX_(2, 1);
#pragma unroll
      for (int f = 0; f < 32; ++f) {
        int fc = ((f & 1) << 12) | (((f >> 1) & 1) << 13) | (((f >> 2) & 1) << 2)
               | (((f >> 3) & 1) << 3) | (((f >> 4) & 1) << 4);
        lds[(tp | fc) ^ mt ^ mixL(fc)] = v[f]; } }
    __syncthreads();

    { int tp = (t & 31) | (((t >> 5) & 1) << 9) | (((t >> 6) & 1) << 8)
             | (((t >> 7) & 1) << 12) | (((t >> 8) & 1) << 13);
      int mt = mixL(tp);
#pragma unroll
      for (int f = 0; f < 32; ++f) {
        int fc = ((f & 1) << 10) | (((f >> 1) & 1) << 5) | (((f >> 2) & 1) << 6)
               | (((f >> 3) & 1) << 7) | (((f >> 4) & 1) << 11);
        v[f] = lds[(tp | fc) ^ mt ^ mixL(fc)]; }
      RYT_(csl, 16, 12); RYT_(csl, 8, 13); RYT_(csl, 4, 14); RYT_(csl, 2, 15); RYT_(csl, 1, 16);
      CXI_((t >> 7) & 1, 16); CX_(16, 8); CX_(8, 4); CX_(4, 2); CX_(2, 1);
#pragma unroll
      for (int f = 0; f < 32; ++f) {
        int fc = ((f & 1) << 10) | (((f >> 1) & 1) << 5) | (((f >> 2) & 1) << 6)
               | (((f >> 3) & 1) << 7) | (((f >> 4) & 1) << 11);
        lds[(tp | fc) ^ mt ^ mixL(fc)] = v[f]; } }
    __syncthreads();

    { int tp;
      if (!fin)
        tp = ((t & 1) << 2) | (((t >> 1) & 1) << 3) | (((t >> 2) & 1) << 4)
           | (((t >> 3) & 1) << 10) | (((t >> 4) & 1) << 5) | (((t >> 5) & 1) << 6)
           | (((t >> 6) & 1) << 1) | (((t >> 7) & 1) << 12) | (((t >> 8) & 1) << 13);
      else
        tp = ((t & 1) << 10) | (((t >> 1) & 1) << 5) | (((t >> 2) & 1) << 6)
           | (((t >> 3) & 1) << 12) | (((t >> 4) & 1) << 13) | (((t >> 5) & 1) << 2)
           | (((t >> 6) & 1) << 1) | (((t >> 7) & 1) << 3) | (((t >> 8) & 1) << 4);
      int mt = mixL(tp);
#pragma unroll
      for (int u = 0; u < 32; ++u) {
        int fc = ((u & 1) << 0) | (((u >> 1) & 1) << 8) | (((u >> 2) & 1) << 9)
               | (((u >> 3) & 1) << 7) | (((u >> 4) & 1) << 11);
        v[u] = lds[(tp | fc) ^ mt ^ mixL(fc)]; }
      RYT_(csl, 4, 17); RYT_(csl, 2, 18);
      { int e3 = fin ? (t & 1) : ((t >> 3) & 1);
        CXI_(e3, 4); }
      CX_(4, 2); CX_(2, 1);
      if (!fin) {
        int sb = (blk << 12) + (t & 7) + (((t >> 3) & 7) << 6)
               + (((t >> 7) & 3) << 9) + (((t >> 6) & 1) << 11);
#pragma unroll
        for (int g = 0; g < 8; ++g) {
          int bu = ((g >> 2) & 1) | (((g >> 1) & 1) << 1) | ((g & 1) << 2);
          dsth[sb + (g << 3)] = make_uint2(pk2(v[bu], v[bu | 8]), pk2(v[bu | 16], v[bu | 24]));
        }
      } else {
        int sb = (blk << 12) + ((t & 7) << 1) + (((t >> 3) & 7) << 6)
               + (((t >> 7) & 1) << 9) + (((t >> 8) & 1) << 10) + (((t >> 6) & 1) << 11);
#pragma unroll
        for (int g = 0; g < 8; ++g) {
          int bu = ((g & 1) << 2) | (((g >> 1) & 1) << 3) | (((g >> 2) & 1) << 4);
          dstf[sb + (g & 1) + (((g >> 1) & 1) << 4) + (((g >> 2) & 1) << 5)] =
            make_float4(fabsf(v[bu]), fabsf(v[bu | 1]), fabsf(v[bu | 2]), fabsf(v[bu | 3]));
        }
      } }
}

// ---------------- Persistent scheduler ----------------
__global__ __launch_bounds__(512, 2) void qsim(
    const float4* __restrict__ x, float4* __restrict__ outF,
    uint2* __restrict__ B0, uint2* __restrict__ B1,
    const float2* __restrict__ cs, int* __restrict__ ctrl)
{
    __shared__ float lds[16384];
    __shared__ int stk;
    int t = threadIdx.x;
    int* ticket = ctrl;
    int* done = ctrl + 1;   // done[p*16+b], p=0..5

    for (;;) {
        __syncthreads();                       // protect stk + lds reuse
        if (t == 0) stk = atomicAdd(ticket, 1);
        __syncthreads();
        int tk = stk;
        if (tk >= NT) break;                   // uniform exit
        int p = tk >> 10, r = tk & 1023, b = r >> 6, G = r & 63;
        int blk = (b << 6) | G;

        if (p > 0) {                           // wait for pass p-1, batch b
            if (t == 0) {
                int* f = done + (p - 1) * 16 + b;
                long spins = 0;
                while (__hip_atomic_load(f, __ATOMIC_RELAXED, __HIP_MEMORY_SCOPE_AGENT) < 64) {
                    __builtin_amdgcn_s_sleep(8);
                    if (++spins > (1L << 18)) break;   // bounded: bug -> wrong, not hang
                }
                __threadfence();               // acquire: invalidate L1/L2
            }
            __syncthreads();
        }

        if (p == 0)      body_R(x, B0, cs, blk, t, lds);
        else if (p == 1) body_A(B0, B1, cs, 0, false, blk, t, lds);
        else if (p == 2) body_F(B1, B0, cs, 0, false, blk, t, lds);
        else if (p == 3) body_L(B0, nullptr, B1, cs, 1, false, blk, t, lds);
        else if (p == 4) body_A(B1, B0, cs, 2, true, blk, t, lds);
        else if (p == 5) body_F(B0, B1, cs, 2, true, blk, t, lds);
        else             body_L(B1, outF, nullptr, cs, 3, true, blk, t, lds);

        __syncthreads();                       // drains vmcnt(0): stores in L2
        if (p < 6 && t == 0) {
            __threadfence();                   // release: writeback L2
            atomicAdd(done + p * 16 + b, 1);
        }
    }
}

extern "C" void kernel_launch(void* const* d_in, const int* in_sizes, int n_in,
                              void* d_out, int out_size, void* d_ws, size_t ws_size,
                              hipStream_t stream) {
    const float* x     = (const float*)d_in[0];   // (16, 2^20) f32, standard layout
    const float* theta = (const float*)d_in[1];   // (80,) f32
    float2* cs = (float2*)d_ws;                   // 80 (cos,sin) pairs @ +0
    int* ctrl  = (int*)((char*)d_ws + 1024);      // ticket + 96 done flags
    uint2* B0  = (uint2*)((char*)d_ws + 4096);            // 32 MB fp16 state
    uint2* B1  = (uint2*)((char*)d_ws + 4096 + (32u<<20)); // 32 MB fp16 state
    float4* outF = (float4*)d_out;

    cs_zero_kernel<<<1, 128, 0, stream>>>(theta, cs, ctrl);
    qsim<<<512, 512, 0, stream>>>((const float4*)x, outF, B0, B1, cs, ctrl);
}

// Round 10
// 793.232 us; speedup vs baseline: 1.6666x; 1.3882x over previous
//
#include <hip/hip_runtime.h>
#include <hip/hip_fp16.h>
#include <math.h>

// Quantum circuit sim, 20 qubits, 4 layers, batch 16, purely-real f32 state.
// Element bit Ek <-> qubit q = 19-k. Same 7-pass math as the verified 257-us
// fp16 kernel (R A F L A* F* L*), fused into ONE PERSISTENT KERNEL with a
// REGION-STRUCTURED scheduler:
//   - 7 per-pass ticket counters; a block drains pass p's 1024 tickets
//     (b-major), then falls through to pass p+1. Fast blocks run ahead into
//     p+1 (waiting on done[p][b]==64 per batch) while stragglers finish p ->
//     soft per-batch boundaries, no global syncs, no 7-way switch.
//   - R9 lesson: the single-loop switch scheduler kept ticket/pointer state
//     live across all 7 inlined bodies -> demand ~150 VGPR vs the 128 cap
//     (LDS 66KB -> 2 blocks/CU -> 4 waves/EU -> 128 budget) -> 1.35 GB spill
//     traffic. Seven sequential region loops isolate live ranges: pressure ~
//     standalone body (112, R4) + small loop state. readfirstlane puts the
//     ticket in SGPR so b/blk/flag addresses are scalar.
//   - Sync scheme unchanged from R8/R9 (passed on HW): grab ticket ->
//     t0 bounded-spin on done[p-1][b] + threadfence acquire -> barrier ->
//     body -> barrier (drains vmcnt) -> t0 threadfence release + atomicAdd.
//   - Deadlock-free by induction on (pass, ticket) lexicographic order.
//   - fp16 intermediates in two dedicated 32MB ws buffers (L3-resident).

__global__ void cs_zero_kernel(const float* __restrict__ theta,
                               float2* __restrict__ cs, int* __restrict__ ctrl) {
    int i = threadIdx.x;
    if (i < 80) {
        float s, c;
        sincosf(theta[i] * 0.5f, &s, &c);
        cs[i] = make_float2(c, s);
    }
    if (i < 128) ctrl[i] = 0;   // [0..6]=per-pass tickets, [8..103]=done flags
}

union H2U { __half2 h; unsigned u; };
__device__ __forceinline__ unsigned pk2(float a, float b) {
    H2U x; x.h = __float22half2_rn(make_float2(a, b)); return x.u;
}
__device__ __forceinline__ float2 upk2(unsigned u) {
    H2U x; x.u = u; return __half22float2(x.h);
}

// RY on fragment bit MASK with angle table TBL[Q]
#define RYT_(TBL, MASK, Q) { float2 _sc = (TBL)[(Q)]; float _c = _sc.x, _s = _sc.y; \
  _Pragma("unroll") for (int _m = 0; _m < 32; ++_m) if (!(_m & (MASK))) { \
    float _a = v[_m], _b = v[_m | (MASK)]; \
    v[_m] = _c*_a - _s*_b; v[_m | (MASK)] = _s*_a + _c*_b; } }

// CNOT: control mask CM, target mask TM, both in fragment
#define CX_(CM, TM) { _Pragma("unroll") for (int _m = 0; _m < 32; ++_m) \
  if ((_m & (CM)) && !(_m & (TM))) { float _t = v[_m]; v[_m] = v[_m|(TM)]; v[_m|(TM)] = _t; } }

// CNOT with control on a thread-index bit (COND), target mask TM in fragment
#define CXI_(COND, TM) { if (COND) { _Pragma("unroll") for (int _m = 0; _m < 32; ++_m) \
  if (!(_m & (TM))) { float _t = v[_m]; v[_m] = v[_m|(TM)]; v[_m|(TM)] = _t; } } }

__device__ __forceinline__ int mixR(int n) {
    return ((n >> 5) & 31) ^ ((n >> 10) & 1);
}
__device__ __forceinline__ int mixA(int n) {
    return ((n >> 5) & 31) ^ ((n >> 10) & 1) ^ (((n >> 11) & 1) << 3)
         ^ (((n >> 12) & 1) << 4) ^ (((n >> 13) & 1) << 4);
}
__device__ __forceinline__ int mixF(int n) {
    return ((n >> 5) & 31) ^ (((n >> 10) & 1) << 1) ^ (((n >> 11) & 1) << 2)
         ^ (((n >> 12) & 1) << 3) ^ (((n >> 13) & 1) << 4);
}
__device__ __forceinline__ int mixL(int n) {
    return ((n >> 5) & 31) ^ (((n >> 10) & 1) << 4) ^ (((n >> 11) & 1) << 2)
         ^ (((n >> 12) & 1) << 3) ^ (((n >> 13) & 1) << 4);
}

// ---------------- Pass R body: std(f32) -> B(fp16), RY on E13..E0 (layer 0) --
__device__ __forceinline__ void body_R(const float4* __restrict__ src,
    uint2* __restrict__ dst, const float2* __restrict__ cs,
    int blk, int t, float* lds)
{
    const float2* csl = cs;                       // layer 0
    int H = blk & 63, b = blk >> 6;
    int base = (b << 18) + (H << 12);
    float v[32];

#pragma unroll
    for (int i = 0; i < 8; ++i) {
        float4 w = src[base + (i << 8) + (((t >> 6) & 3) << 6) + (((t >> 8) & 1) << 11) + (t & 63)];
        v[i*4+0] = w.x; v[i*4+1] = w.y; v[i*4+2] = w.z; v[i*4+3] = w.w;
    }
    RYT_(csl, 1, 19); RYT_(csl, 2, 18); RYT_(csl, 4, 9); RYT_(csl, 8, 8); RYT_(csl, 16, 7);
    { int w1x = (t & 31) ^ ((t >> 5) & 1);
#pragma unroll
      for (int m = 0; m < 32; ++m) lds[(t << 5) | (m ^ w1x)] = v[m]; }
    __syncthreads();

    { int tp = (t & 31) | (((t >> 5) & 1) << 10) | (((t >> 6) & 7) << 11);
      int mt = mixR(tp);
#pragma unroll
      for (int f = 0; f < 32; ++f) { int fc = f << 5; v[f] = lds[(tp | fc) ^ mt ^ mixR(fc)]; }
      RYT_(csl, 1, 17); RYT_(csl, 2, 16); RYT_(csl, 4, 15); RYT_(csl, 8, 14); RYT_(csl, 16, 13);
#pragma unroll
      for (int f = 0; f < 32; ++f) { int fc = f << 5; lds[(tp | fc) ^ mt ^ mixR(fc)] = v[f]; } }
    __syncthreads();

    { int tp = ((t & 1) << 2) | (((t >> 1) & 1) << 3) | (((t >> 2) & 1) << 4)
             | (((t >> 3) & 1) << 5) | (((t >> 4) & 1) << 1) | (((t >> 5) & 1) << 0)
             | (((t >> 6) & 7) << 6);
      int mt = mixR(tp);
#pragma unroll
      for (int p = 0; p < 32; ++p) { int fc = p << 9; v[p] = lds[(tp | fc) ^ mt ^ mixR(fc)]; }
      RYT_(csl, 2, 12); RYT_(csl, 4, 11); RYT_(csl, 8, 10); RYT_(csl, 16, 6);
      int sb = base + (((t >> 6) & 7) << 6) + (t & 63);
#pragma unroll
      for (int j = 0; j < 8; ++j)
        dst[sb + (j << 9)] = make_uint2(pk2(v[4*j], v[4*j+1]), pk2(v[4*j+2], v[4*j+3])); }
}

// ---------------- Pass A body: M -> P (fp16) --------------------------------
__device__ __forceinline__ void body_A(const uint2* __restrict__ src,
    uint2* __restrict__ dst, const float2* __restrict__ cs,
    int layer, bool full, int blk, int t, float* lds)
{
    const float2* csl = cs + layer * 20;
    int G = blk & 63, b = blk >> 6;
    int Gperm = ((G >> 2) & 1) | (((G >> 1) & 1) << 1) | ((G & 1) << 2) | (((G >> 3) & 7) << 3);
    float v[32];

    { int lb = (b << 18) + (((t >> 6) & 7) << 9) + (Gperm << 3) + (t & 7);
      int rg = ((t >> 3) & 7) << 12;
#pragma unroll
      for (int i = 0; i < 8; ++i) {
        uint2 w = src[lb + ((i << 3) << 12) + rg];
        float2 lo = upk2(w.x), hi = upk2(w.y);
        v[i*4+0] = lo.x; v[i*4+1] = lo.y; v[i*4+2] = hi.x; v[i*4+3] = hi.y;
      } }
    RYT_(csl, 16, 0); RYT_(csl, 8, 1); RYT_(csl, 4, 2);
    if (full) { RYT_(csl, 2, 12); RYT_(csl, 1, 13); }
    { int w1x = (t & 31) ^ ((t >> 5) & 1) ^ (((t >> 6) & 1) << 3)
              ^ (((t >> 7) & 1) << 4) ^ (((t >> 8) & 1) << 4);
#pragma unroll
      for (int m = 0; m < 32; ++m) lds[(t << 5) | (m ^ w1x)] = v[m]; }
    __syncthreads();

    { int tp = (t & 3) | (((t >> 2) & 1) << 7) | (((t >> 3) & 1) << 11)
             | (((t >> 4) & 1) << 12) | (((t >> 5) & 1) << 13) | (((t >> 6) & 1) << 5)
             | (((t >> 7) & 1) << 6) | (((t >> 8) & 1) << 8);
      int mt = mixA(tp);
#pragma unroll
      for (int f = 0; f < 32; ++f) {
        int fc = ((f & 1) << 9) | (((f >> 1) & 1) << 10) | (((f >> 2) & 1) << 2)
               | (((f >> 3) & 1) << 3) | (((f >> 4) & 1) << 4);
        v[f] = lds[(tp | fc) ^ mt ^ mixA(fc)]; }
      RYT_(csl, 1, 4); RYT_(csl, 2, 3);
      CX_(16, 8); CX_(8, 4); CX_(4, 2); CX_(2, 1);
#pragma unroll
      for (int f = 0; f < 32; ++f) {
        int fc = ((f & 1) << 9) | (((f >> 1) & 1) << 10) | (((f >> 2) & 1) << 2)
               | (((f >> 3) & 1) << 3) | (((f >> 4) & 1) << 4);
        lds[(tp | fc) ^ mt ^ mixA(fc)] = v[f]; } }
    __syncthreads();

    { int tp = (t & 31) | (((t >> 5) & 1) << 9) | (((t >> 6) & 1) << 10)
             | (((t >> 7) & 1) << 11) | (((t >> 8) & 1) << 12);
      int mt = mixA(tp);
#pragma unroll
      for (int f = 0; f < 32; ++f) {
        int fc = ((f & 1) << 5) | (((f >> 1) & 1) << 6) | (((f >> 2) & 1) << 7)
               | (((f >> 3) & 1) << 13) | (((f >> 4) & 1) << 8);
        v[f] = lds[(tp | fc) ^ mt ^ mixA(fc)]; }
      RYT_(csl, 16, 5);
      if (full) { RYT_(csl, 8, 6); RYT_(csl, 4, 7); RYT_(csl, 2, 8); RYT_(csl, 1, 9); }
      CXI_((t >> 5) & 1, 16); CX_(16, 8); CX_(8, 4); CX_(4, 2); CX_(2, 1);
#pragma unroll
      for (int f = 0; f < 32; ++f) {
        int fc = ((f & 1) << 5) | (((f >> 1) & 1) << 6) | (((f >> 2) & 1) << 7)
               | (((f >> 3) & 1) << 13) | (((f >> 4) & 1) << 8);
        lds[(tp | fc) ^ mt ^ mixA(fc)] = v[f]; } }
    __syncthreads();

    { int tp = ((t & 1) << 8) | (((t >> 1) & 1) << 9) | (((t >> 2) & 1) << 10)
             | (((t >> 3) & 1) << 6) | (((t >> 4) & 1) << 7) | (((t >> 5) & 1) << 2)
             | (((t >> 6) & 1) << 5) | (((t >> 7) & 1) << 3) | (((t >> 8) & 1) << 4);
      int mt = mixA(tp);
#pragma unroll
      for (int p = 0; p < 32; ++p) {
        int fc = ((p & 1) << 0) | (((p >> 1) & 1) << 13) | (((p >> 2) & 1) << 1)
               | (((p >> 3) & 1) << 11) | (((p >> 4) & 1) << 12);
        v[p] = lds[(tp | fc) ^ mt ^ mixA(fc)]; }
      if (full) { RYT_(csl, 16, 10); RYT_(csl, 8, 11); }
      CXI_((t >> 6) & 1, 16); CX_(16, 8); CX_(8, 4); CX_(4, 1);
      int G2 = blk & 63, b2 = blk >> 6;
      int sb = (b2 << 18) + (G2 << 12) + t;
#pragma unroll
      for (int j = 0; j < 8; ++j)
        dst[sb + (j << 9)] = make_uint2(pk2(v[4*j], v[4*j+1]), pk2(v[4*j+2], v[4*j+3])); }
}

// ---------------- Pass F body: P -> Q (fp16) --------------------------------
__device__ __forceinline__ void body_F(const uint2* __restrict__ src,
    uint2* __restrict__ dst, const float2* __restrict__ cs,
    int layer, bool lowry, int blk, int t, float* lds)
{
    const float2* csl  = cs + layer * 20;
    const float2* csl2 = cs + (layer + 1) * 20;
    int W = blk & 63, b = blk >> 6;
    int Wp = (((W >> 4) & 1) << 3) | (((W >> 5) & 1) << 4) | (((W >> 3) & 1) << 6)
           | ((W & 1) << 9) | (((W >> 1) & 1) << 10) | (((W >> 2) & 1) << 11);
    float v[32];

    { int lb = (((b << 6) | ((t >> 3) & 63)) << 12) + (t & 7) + Wp;
#pragma unroll
      for (int i = 0; i < 8; ++i) {
        uint2 w = src[lb + ((i & 1) << 5) + (((i >> 1) & 1) << 7) + (((i >> 2) & 1) << 8)];
        float2 lo = upk2(w.x), hi = upk2(w.y);
        v[i*4+0] = lo.x; v[i*4+1] = lo.y; v[i*4+2] = hi.x; v[i*4+3] = hi.y;
      } }
    RYT_(csl2, 16, 0); RYT_(csl2, 8, 1); RYT_(csl2, 4, 2); RYT_(csl2, 2, 6);
    CX_(16, 8); CX_(8, 4);
    { int w1x = (t & 31) ^ (((t >> 5) & 1) << 1) ^ (((t >> 6) & 1) << 2)
              ^ (((t >> 7) & 1) << 3) ^ (((t >> 8) & 1) << 4);
#pragma unroll
      for (int m = 0; m < 32; ++m) lds[(t << 5) | (m ^ w1x)] = v[m]; }
    __syncthreads();

    { int tp = (t & 31) | (((t >> 5) & 1) << 8) | (((t >> 6) & 1) << 5)
             | (((t >> 7) & 1) << 6) | (((t >> 8) & 1) << 7);
      int mt = mixF(tp);
#pragma unroll
      for (int f = 0; f < 32; ++f) { int fc = f << 9; v[f] = lds[(tp | fc) ^ mt ^ mixF(fc)]; }
      if (lowry) { RYT_(csl, 16, 14); RYT_(csl, 8, 15); RYT_(csl, 4, 16); RYT_(csl, 2, 17); RYT_(csl, 1, 18); }
      CXI_(t & 1, 16); CX_(16, 8); CX_(8, 4); CX_(4, 2); CX_(2, 1);
#pragma unroll
      for (int f = 0; f < 32; ++f) { int fc = f << 9; lds[(tp | fc) ^ mt ^ mixF(fc)] = v[f]; } }
    __syncthreads();

    { int tp = ((t & 1) << 12) | (((t >> 1) & 1) << 13) | (((t >> 2) & 1) << 0)
             | (((t >> 3) & 1) << 9) | (((t >> 4) & 1) << 10) | (((t >> 5) & 1) << 11)
             | (((t >> 6) & 1) << 2) | (((t >> 7) & 1) << 3) | (((t >> 8) & 1) << 4);
      int mt = mixF(tp);
#pragma unroll
      for (int p = 0; p < 32; ++p) {
        int fc = ((p & 1) << 8) | (((p >> 1) & 1) << 1) | (((p >> 2) & 1) << 5)
               | (((p >> 3) & 1) << 6) | (((p >> 4) & 1) << 7);
        v[p] = lds[(tp | fc) ^ mt ^ mixF(fc)]; }
      if (lowry) { RYT_(csl, 1, 19); }
      CXI_((t >> 3) & 1, 1);
      RYT_(csl2, 16, 3); RYT_(csl2, 8, 4); RYT_(csl2, 4, 5);
      CXI_((t >> 6) & 1, 16); CX_(16, 8); CX_(8, 4); CX_(4, 2);
      int sb = (blk << 12) + t;
#pragma unroll
      for (int j = 0; j < 8; ++j)
        dst[sb + (j << 9)] = make_uint2(pk2(v[4*j], v[4*j+1]), pk2(v[4*j+2], v[4*j+3])); }
}

// ---------------- Pass L body: Q -> M (fp16) or std+abs (f32) ---------------
__device__ __forceinline__ void body_L(const uint2* __restrict__ src,
    float4* __restrict__ dstf, uint2* __restrict__ dsth,
    const float2* __restrict__ cs, int layer, bool fin, int blk, int t, float* lds)
{
    const float2* csl = cs + layer * 20;
    int H = blk & 63, b = blk >> 6;
    int Hp = (((H >> 3) & 7) << 6) | ((H & 7) << 9);
    float v[32];

    { int rb = (b << 6) | ((t >> 6) & 7);
      int lo = Hp + (t & 63);
#pragma unroll
      for (int i = 0; i < 8; ++i) {
        uint2 w = src[((rb | (i << 3)) << 12) + lo];
        float2 l2 = upk2(w.x), h2 = upk2(w.y);
        v[i*4+0] = l2.x; v[i*4+1] = l2.y; v[i*4+2] = h2.x; v[i*4+3] = h2.y;
      } }
    RYT_(csl, 1, 19); RYT_(csl, 4, 9); RYT_(csl, 8, 8); RYT_(csl, 16, 7);
    { int w1x = (t & 31) ^ (((t >> 5) & 1) << 4) ^ (((t >> 6) & 1) << 2)
              ^ (((t >> 7) & 1) << 3) ^ (((t >> 8) & 1) << 4);
#pragma unroll
      for (int m = 0; m < 32; ++m) lds[(t << 5) | (m ^ w1x)] = v[m]; }
    __syncthreads();

    { int tp = (t & 3) | (((t >> 2) & 1) << 7) | (((t >> 3) & 1) << 8)
             | (((t >> 4) & 1) << 9) | (((t >> 5) & 1) << 10) | (((t >> 6) & 1) << 5)
             | (((t >> 7) & 1) << 6) | (((t >> 8) & 1) << 11);
      int mt = mixL(tp);
#pragma unroll
      for (int f = 0; f < 32; ++f) {
        int fc = ((f & 1) << 12) | (((f >> 1) & 1) << 13) | (((f >> 2) & 1) << 2)
               | (((f >> 3) & 1) << 3) | (((f >> 4) & 1) << 4);
        v[f] = lds[(tp | fc) ^ mt ^ mixL(fc)]; }
      RYT_(csl, 2, 10); RYT_(csl, 1, 11);
      CXI_((t >> 1) & 1, 16); CX_(16, 8); CX_(8, 4); CX_(4, 2); CX_(2, 1);
#pragma unroll
      for (int f = 0; f < 32; ++f) {
        int fc = ((f & 1) << 12) | (((f >> 1) & 1) << 13) | (((f >> 2) & 1) << 2)
               | (((f >> 3) & 1) << 3) | (((f >> 4) & 1) << 4);
        lds[(tp | fc) ^ mt ^ mixL(fc)] = v[f]; } }
    __syncthreads();

    { int tp = (t & 31) | (((t >> 5) & 1) << 9) | (((t >> 6) & 1) << 8)
             | (((t >> 7) & 1) << 12) | (((t >> 8) & 1) << 13);
      int mt = mixL(tp);
#pragma unroll
      for (int f = 0; f < 32; ++f) {
        int fc = ((f & 1) << 10) | (((f >> 1) & 1) << 5) | (((f >> 2) & 1) << 6)
               | (((f >> 3) & 1) << 7) | (((f >> 4) & 1) << 11);
        v[f] = lds[(tp | fc) ^ mt ^ mixL(fc)]; }
      RYT_(csl, 16, 12); RYT_(csl, 8, 13); RYT_(csl, 4, 14); RYT_(csl, 2, 15); RYT_(csl, 1, 16);
      CXI_((t >> 7) & 1, 16); CX_(16, 8); CX_(8, 4); CX_(4, 2); CX_(2, 1);
#pragma unroll
      for (int f = 0; f < 32; ++f) {
        int fc = ((f & 1) << 10) | (((f >> 1) & 1) << 5) | (((f >> 2) & 1) << 6)
               | (((f >> 3) & 1) << 7) | (((f >> 4) & 1) << 11);
        lds[(tp | fc) ^ mt ^ mixL(fc)] = v[f]; } }
    __syncthreads();

    { int tp;
      if (!fin)
        tp = ((t & 1) << 2) | (((t >> 1) & 1) << 3) | (((t >> 2) & 1) << 4)
           | (((t >> 3) & 1) << 10) | (((t >> 4) & 1) << 5) | (((t >> 5) & 1) << 6)
           | (((t >> 6) & 1) << 1) | (((t >> 7) & 1) << 12) | (((t >> 8) & 1) << 13);
      else
        tp = ((t & 1) << 10) | (((t >> 1) & 1) << 5) | (((t >> 2) & 1) << 6)
           | (((t >> 3) & 1) << 12) | (((t >> 4) & 1) << 13) | (((t >> 5) & 1) << 2)
           | (((t >> 6) & 1) << 1) | (((t >> 7) & 1) << 3) | (((t >> 8) & 1) << 4);
      int mt = mixL(tp);
#pragma unroll
      for (int u = 0; u < 32; ++u) {
        int fc = ((u & 1) << 0) | (((u >> 1) & 1) << 8) | (((u >> 2) & 1) << 9)
               | (((u >> 3) & 1) << 7) | (((u >> 4) & 1) << 11);
        v[u] = lds[(tp | fc) ^ mt ^ mixL(fc)]; }
      RYT_(csl, 4, 17); RYT_(csl, 2, 18);
      { int e3 = fin ? (t & 1) : ((t >> 3) & 1);
        CXI_(e3, 4); }
      CX_(4, 2); CX_(2, 1);
      if (!fin) {
        int sb = (blk << 12) + (t & 7) + (((t >> 3) & 7) << 6)
               + (((t >> 7) & 3) << 9) + (((t >> 6) & 1) << 11);
#pragma unroll
        for (int g = 0; g < 8; ++g) {
          int bu = ((g >> 2) & 1) | (((g >> 1) & 1) << 1) | ((g & 1) << 2);
          dsth[sb + (g << 3)] = make_uint2(pk2(v[bu], v[bu | 8]), pk2(v[bu | 16], v[bu | 24]));
        }
      } else {
        int sb = (blk << 12) + ((t & 7) << 1) + (((t >> 3) & 7) << 6)
               + (((t >> 7) & 1) << 9) + (((t >> 8) & 1) << 10) + (((t >> 6) & 1) << 11);
#pragma unroll
        for (int g = 0; g < 8; ++g) {
          int bu = ((g & 1) << 2) | (((g >> 1) & 1) << 3) | (((g >> 2) & 1) << 4);
          dstf[sb + (g & 1) + (((g >> 1) & 1) << 4) + (((g >> 2) & 1) << 5)] =
            make_float4(fabsf(v[bu]), fabsf(v[bu | 1]), fabsf(v[bu | 2]), fabsf(v[bu | 3]));
        }
      } }
}

// ---------------- Region-structured persistent scheduler ----------------
// One ticket loop per pass, sequential; fast blocks fall through into the
// next pass while stragglers finish the current one (soft per-batch deps).
#define QREGION(P, CALLBODY) \
  for (;;) { \
    __syncthreads();                    /* protect stk + lds reuse */ \
    if (t == 0) stk = atomicAdd(&tickets[P], 1); \
    __syncthreads(); \
    int tk = __builtin_amdgcn_readfirstlane(stk); \
    if (tk >= 1024) break; \
    int b = tk >> 6; int blk = tk; (void)b; \
    if ((P) > 0) { \
      if (t == 0) { \
        int* f = done + ((P) - 1) * 16 + b; \
        long spins = 0; \
        while (__hip_atomic_load(f, __ATOMIC_RELAXED, __HIP_MEMORY_SCOPE_AGENT) < 64) { \
          __builtin_amdgcn_s_sleep(8); \
          if (++spins > (1L << 18)) break;   /* bounded: bug -> wrong, not hang */ \
        } \
        __threadfence();                /* acquire */ \
      } \
      __syncthreads(); \
    } \
    CALLBODY; \
    __syncthreads();                    /* drains vmcnt: stores in L2 */ \
    if ((P) < 6 && t == 0) { __threadfence(); atomicAdd(done + (P) * 16 + b, 1); } \
  }

__global__ __launch_bounds__(512, 2) void qsim(
    const float4* __restrict__ x, float4* __restrict__ outF,
    uint2* __restrict__ B0, uint2* __restrict__ B1,
    const float2* __restrict__ cs, int* __restrict__ ctrl)
{
    __shared__ float lds[16384];
    __shared__ int stk;
    int t = threadIdx.x;
    int* tickets = ctrl;      // [0..6] per-pass ticket counters
    int* done = ctrl + 8;     // done[p*16+b], p=0..5

    QREGION(0, body_R(x, B0, cs, blk, t, lds));
    QREGION(1, body_A(B0, B1, cs, 0, false, blk, t, lds));
    QREGION(2, body_F(B1, B0, cs, 0, false, blk, t, lds));
    QREGION(3, body_L(B0, nullptr, B1, cs, 1, false, blk, t, lds));
    QREGION(4, body_A(B1, B0, cs, 2, true, blk, t, lds));
    QREGION(5, body_F(B0, B1, cs, 2, true, blk, t, lds));
    QREGION(6, body_L(B1, outF, nullptr, cs, 3, true, blk, t, lds));
}

extern "C" void kernel_launch(void* const* d_in, const int* in_sizes, int n_in,
                              void* d_out, int out_size, void* d_ws, size_t ws_size,
                              hipStream_t stream) {
    const float* x     = (const float*)d_in[0];   // (16, 2^20) f32, standard layout
    const float* theta = (const float*)d_in[1];   // (80,) f32
    float2* cs = (float2*)d_ws;                   // 80 (cos,sin) pairs @ +0
    int* ctrl  = (int*)((char*)d_ws + 1024);      // 7 tickets + 96 done flags
    uint2* B0  = (uint2*)((char*)d_ws + 4096);            // 32 MB fp16 state
    uint2* B1  = (uint2*)((char*)d_ws + 4096 + (32u<<20)); // 32 MB fp16 state
    float4* outF = (float4*)d_out;

    cs_zero_kernel<<<1, 128, 0, stream>>>(theta, cs, ctrl);
    qsim<<<512, 512, 0, stream>>>((const float4*)x, outF, B0, B1, cs, ctrl);
}

// Round 11
// 695.322 us; speedup vs baseline: 1.9013x; 1.1408x over previous
//
#include <hip/hip_runtime.h>
#include <hip/hip_fp16.h>
#include <math.h>

// Quantum circuit sim, 20 qubits, 4 layers, batch 16, purely-real f32 state.
// Element bit Ek <-> qubit q = 19-k. Same 7-pass math as the verified 257-us
// fp16 kernel (R A F L A* F* L*), fused into ONE PERSISTENT KERNEL with a
// REGION-STRUCTURED scheduler:
//   - 7 per-pass ticket counters; a block drains pass p's 1024 tickets
//     (b-major), then falls through to pass p+1. Fast blocks run ahead into
//     p+1 (waiting on done[p][b]==64 per batch) while stragglers finish p.
//   - R10 lesson: region loops alone still spilled (VGPR capped at 128,
//     ~500MB scratch traffic). Mechanism: LICM hoists each body's t-only-
//     dependent address math (tp/mt/w1x/load offsets, 5-8 values x 7 bodies)
//     out of the ticket loops to function entry -> ~40-50 extra live VGPRs
//     across all regions. FIX: opaque per-iteration copy of t
//     (asm volatile "+v") passed to the body — pins all t-derived math
//     inside its own region loop. Cost: ~8 recomputed VALU ops per ticket.
//   - Sync scheme unchanged from R8/R9/R10 (passed 3x on HW): grab ticket ->
//     t0 bounded-spin on done[p-1][b] + threadfence acquire -> barrier ->
//     body -> barrier (drains vmcnt) -> t0 threadfence release + atomicAdd.
//   - Deadlock-free by induction on (pass, ticket) lexicographic order.
//   - fp16 intermediates in two dedicated 32MB ws buffers (L3-resident).

__global__ void cs_zero_kernel(const float* __restrict__ theta,
                               float2* __restrict__ cs, int* __restrict__ ctrl) {
    int i = threadIdx.x;
    if (i < 80) {
        float s, c;
        sincosf(theta[i] * 0.5f, &s, &c);
        cs[i] = make_float2(c, s);
    }
    if (i < 128) ctrl[i] = 0;   // [0..6]=per-pass tickets, [8..103]=done flags
}

union H2U { __half2 h; unsigned u; };
__device__ __forceinline__ unsigned pk2(float a, float b) {
    H2U x; x.h = __float22half2_rn(make_float2(a, b)); return x.u;
}
__device__ __forceinline__ float2 upk2(unsigned u) {
    H2U x; x.u = u; return __half22float2(x.h);
}

// RY on fragment bit MASK with angle table TBL[Q]
#define RYT_(TBL, MASK, Q) { float2 _sc = (TBL)[(Q)]; float _c = _sc.x, _s = _sc.y; \
  _Pragma("unroll") for (int _m = 0; _m < 32; ++_m) if (!(_m & (MASK))) { \
    float _a = v[_m], _b = v[_m | (MASK)]; \
    v[_m] = _c*_a - _s*_b; v[_m | (MASK)] = _s*_a + _c*_b; } }

// CNOT: control mask CM, target mask TM, both in fragment
#define CX_(CM, TM) { _Pragma("unroll") for (int _m = 0; _m < 32; ++_m) \
  if ((_m & (CM)) && !(_m & (TM))) { float _t = v[_m]; v[_m] = v[_m|(TM)]; v[_m|(TM)] = _t; } }

// CNOT with control on a thread-index bit (COND), target mask TM in fragment
#define CXI_(COND, TM) { if (COND) { _Pragma("unroll") for (int _m = 0; _m < 32; ++_m) \
  if (!(_m & (TM))) { float _t = v[_m]; v[_m] = v[_m|(TM)]; v[_m|(TM)] = _t; } } }

__device__ __forceinline__ int mixR(int n) {
    return ((n >> 5) & 31) ^ ((n >> 10) & 1);
}
__device__ __forceinline__ int mixA(int n) {
    return ((n >> 5) & 31) ^ ((n >> 10) & 1) ^ (((n >> 11) & 1) << 3)
         ^ (((n >> 12) & 1) << 4) ^ (((n >> 13) & 1) << 4);
}
__device__ __forceinline__ int mixF(int n) {
    return ((n >> 5) & 31) ^ (((n >> 10) & 1) << 1) ^ (((n >> 11) & 1) << 2)
         ^ (((n >> 12) & 1) << 3) ^ (((n >> 13) & 1) << 4);
}
__device__ __forceinline__ int mixL(int n) {
    return ((n >> 5) & 31) ^ (((n >> 10) & 1) << 4) ^ (((n >> 11) & 1) << 2)
         ^ (((n >> 12) & 1) << 3) ^ (((n >> 13) & 1) << 4);
}

// ---------------- Pass R body: std(f32) -> B(fp16), RY on E13..E0 (layer 0) --
__device__ __forceinline__ void body_R(const float4* __restrict__ src,
    uint2* __restrict__ dst, const float2* __restrict__ cs,
    int blk, int t, float* lds)
{
    const float2* csl = cs;                       // layer 0
    int H = blk & 63, b = blk >> 6;
    int base = (b << 18) + (H << 12);
    float v[32];

#pragma unroll
    for (int i = 0; i < 8; ++i) {
        float4 w = src[base + (i << 8) + (((t >> 6) & 3) << 6) + (((t >> 8) & 1) << 11) + (t & 63)];
        v[i*4+0] = w.x; v[i*4+1] = w.y; v[i*4+2] = w.z; v[i*4+3] = w.w;
    }
    RYT_(csl, 1, 19); RYT_(csl, 2, 18); RYT_(csl, 4, 9); RYT_(csl, 8, 8); RYT_(csl, 16, 7);
    { int w1x = (t & 31) ^ ((t >> 5) & 1);
#pragma unroll
      for (int m = 0; m < 32; ++m) lds[(t << 5) | (m ^ w1x)] = v[m]; }
    __syncthreads();

    { int tp = (t & 31) | (((t >> 5) & 1) << 10) | (((t >> 6) & 7) << 11);
      int mt = mixR(tp);
#pragma unroll
      for (int f = 0; f < 32; ++f) { int fc = f << 5; v[f] = lds[(tp | fc) ^ mt ^ mixR(fc)]; }
      RYT_(csl, 1, 17); RYT_(csl, 2, 16); RYT_(csl, 4, 15); RYT_(csl, 8, 14); RYT_(csl, 16, 13);
#pragma unroll
      for (int f = 0; f < 32; ++f) { int fc = f << 5; lds[(tp | fc) ^ mt ^ mixR(fc)] = v[f]; } }
    __syncthreads();

    { int tp = ((t & 1) << 2) | (((t >> 1) & 1) << 3) | (((t >> 2) & 1) << 4)
             | (((t >> 3) & 1) << 5) | (((t >> 4) & 1) << 1) | (((t >> 5) & 1) << 0)
             | (((t >> 6) & 7) << 6);
      int mt = mixR(tp);
#pragma unroll
      for (int p = 0; p < 32; ++p) { int fc = p << 9; v[p] = lds[(tp | fc) ^ mt ^ mixR(fc)]; }
      RYT_(csl, 2, 12); RYT_(csl, 4, 11); RYT_(csl, 8, 10); RYT_(csl, 16, 6);
      int sb = base + (((t >> 6) & 7) << 6) + (t & 63);
#pragma unroll
      for (int j = 0; j < 8; ++j)
        dst[sb + (j << 9)] = make_uint2(pk2(v[4*j], v[4*j+1]), pk2(v[4*j+2], v[4*j+3])); }
}

// ---------------- Pass A body: M -> P (fp16) --------------------------------
__device__ __forceinline__ void body_A(const uint2* __restrict__ src,
    uint2* __restrict__ dst, const float2* __restrict__ cs,
    int layer, bool full, int blk, int t, float* lds)
{
    const float2* csl = cs + layer * 20;
    int G = blk & 63, b = blk >> 6;
    int Gperm = ((G >> 2) & 1) | (((G >> 1) & 1) << 1) | ((G & 1) << 2) | (((G >> 3) & 7) << 3);
    float v[32];

    { int lb = (b << 18) + (((t >> 6) & 7) << 9) + (Gperm << 3) + (t & 7);
      int rg = ((t >> 3) & 7) << 12;
#pragma unroll
      for (int i = 0; i < 8; ++i) {
        uint2 w = src[lb + ((i << 3) << 12) + rg];
        float2 lo = upk2(w.x), hi = upk2(w.y);
        v[i*4+0] = lo.x; v[i*4+1] = lo.y; v[i*4+2] = hi.x; v[i*4+3] = hi.y;
      } }
    RYT_(csl, 16, 0); RYT_(csl, 8, 1); RYT_(csl, 4, 2);
    if (full) { RYT_(csl, 2, 12); RYT_(csl, 1, 13); }
    { int w1x = (t & 31) ^ ((t >> 5) & 1) ^ (((t >> 6) & 1) << 3)
              ^ (((t >> 7) & 1) << 4) ^ (((t >> 8) & 1) << 4);
#pragma unroll
      for (int m = 0; m < 32; ++m) lds[(t << 5) | (m ^ w1x)] = v[m]; }
    __syncthreads();

    { int tp = (t & 3) | (((t >> 2) & 1) << 7) | (((t >> 3) & 1) << 11)
             | (((t >> 4) & 1) << 12) | (((t >> 5) & 1) << 13) | (((t >> 6) & 1) << 5)
             | (((t >> 7) & 1) << 6) | (((t >> 8) & 1) << 8);
      int mt = mixA(tp);
#pragma unroll
      for (int f = 0; f < 32; ++f) {
        int fc = ((f & 1) << 9) | (((f >> 1) & 1) << 10) | (((f >> 2) & 1) << 2)
               | (((f >> 3) & 1) << 3) | (((f >> 4) & 1) << 4);
        v[f] = lds[(tp | fc) ^ mt ^ mixA(fc)]; }
      RYT_(csl, 1, 4); RYT_(csl, 2, 3);
      CX_(16, 8); CX_(8, 4); CX_(4, 2); CX_(2, 1);
#pragma unroll
      for (int f = 0; f < 32; ++f) {
        int fc = ((f & 1) << 9) | (((f >> 1) & 1) << 10) | (((f >> 2) & 1) << 2)
               | (((f >> 3) & 1) << 3) | (((f >> 4) & 1) << 4);
        lds[(tp | fc) ^ mt ^ mixA(fc)] = v[f]; } }
    __syncthreads();

    { int tp = (t & 31) | (((t >> 5) & 1) << 9) | (((t >> 6) & 1) << 10)
             | (((t >> 7) & 1) << 11) | (((t >> 8) & 1) << 12);
      int mt = mixA(tp);
#pragma unroll
      for (int f = 0; f < 32; ++f) {
        int fc = ((f & 1) << 5) | (((f >> 1) & 1) << 6) | (((f >> 2) & 1) << 7)
               | (((f >> 3) & 1) << 13) | (((f >> 4) & 1) << 8);
        v[f] = lds[(tp | fc) ^ mt ^ mixA(fc)]; }
      RYT_(csl, 16, 5);
      if (full) { RYT_(csl, 8, 6); RYT_(csl, 4, 7); RYT_(csl, 2, 8); RYT_(csl, 1, 9); }
      CXI_((t >> 5) & 1, 16); CX_(16, 8); CX_(8, 4); CX_(4, 2); CX_(2, 1);
#pragma unroll
      for (int f = 0; f < 32; ++f) {
        int fc = ((f & 1) << 5) | (((f >> 1) & 1) << 6) | (((f >> 2) & 1) << 7)
               | (((f >> 3) & 1) << 13) | (((f >> 4) & 1) << 8);
        lds[(tp | fc) ^ mt ^ mixA(fc)] = v[f]; } }
    __syncthreads();

    { int tp = ((t & 1) << 8) | (((t >> 1) & 1) << 9) | (((t >> 2) & 1) << 10)
             | (((t >> 3) & 1) << 6) | (((t >> 4) & 1) << 7) | (((t >> 5) & 1) << 2)
             | (((t >> 6) & 1) << 5) | (((t >> 7) & 1) << 3) | (((t >> 8) & 1) << 4);
      int mt = mixA(tp);
#pragma unroll
      for (int p = 0; p < 32; ++p) {
        int fc = ((p & 1) << 0) | (((p >> 1) & 1) << 13) | (((p >> 2) & 1) << 1)
               | (((p >> 3) & 1) << 11) | (((p >> 4) & 1) << 12);
        v[p] = lds[(tp | fc) ^ mt ^ mixA(fc)]; }
      if (full) { RYT_(csl, 16, 10); RYT_(csl, 8, 11); }
      CXI_((t >> 6) & 1, 16); CX_(16, 8); CX_(8, 4); CX_(4, 1);
      int G2 = blk & 63, b2 = blk >> 6;
      int sb = (b2 << 18) + (G2 << 12) + t;
#pragma unroll
      for (int j = 0; j < 8; ++j)
        dst[sb + (j << 9)] = make_uint2(pk2(v[4*j], v[4*j+1]), pk2(v[4*j+2], v[4*j+3])); }
}

// ---------------- Pass F body: P -> Q (fp16) --------------------------------
__device__ __forceinline__ void body_F(const uint2* __restrict__ src,
    uint2* __restrict__ dst, const float2* __restrict__ cs,
    int layer, bool lowry, int blk, int t, float* lds)
{
    const float2* csl  = cs + layer * 20;
    const float2* csl2 = cs + (layer + 1) * 20;
    int W = blk & 63, b = blk >> 6;
    int Wp = (((W >> 4) & 1) << 3) | (((W >> 5) & 1) << 4) | (((W >> 3) & 1) << 6)
           | ((W & 1) << 9) | (((W >> 1) & 1) << 10) | (((W >> 2) & 1) << 11);
    float v[32];

    { int lb = (((b << 6) | ((t >> 3) & 63)) << 12) + (t & 7) + Wp;
#pragma unroll
      for (int i = 0; i < 8; ++i) {
        uint2 w = src[lb + ((i & 1) << 5) + (((i >> 1) & 1) << 7) + (((i >> 2) & 1) << 8)];
        float2 lo = upk2(w.x), hi = upk2(w.y);
        v[i*4+0] = lo.x; v[i*4+1] = lo.y; v[i*4+2] = hi.x; v[i*4+3] = hi.y;
      } }
    RYT_(csl2, 16, 0); RYT_(csl2, 8, 1); RYT_(csl2, 4, 2); RYT_(csl2, 2, 6);
    CX_(16, 8); CX_(8, 4);
    { int w1x = (t & 31) ^ (((t >> 5) & 1) << 1) ^ (((t >> 6) & 1) << 2)
              ^ (((t >> 7) & 1) << 3) ^ (((t >> 8) & 1) << 4);
#pragma unroll
      for (int m = 0; m < 32; ++m) lds[(t << 5) | (m ^ w1x)] = v[m]; }
    __syncthreads();

    { int tp = (t & 31) | (((t >> 5) & 1) << 8) | (((t >> 6) & 1) << 5)
             | (((t >> 7) & 1) << 6) | (((t >> 8) & 1) << 7);
      int mt = mixF(tp);
#pragma unroll
      for (int f = 0; f < 32; ++f) { int fc = f << 9; v[f] = lds[(tp | fc) ^ mt ^ mixF(fc)]; }
      if (lowry) { RYT_(csl, 16, 14); RYT_(csl, 8, 15); RYT_(csl, 4, 16); RYT_(csl, 2, 17); RYT_(csl, 1, 18); }
      CXI_(t & 1, 16); CX_(16, 8); CX_(8, 4); CX_(4, 2); CX_(2, 1);
#pragma unroll
      for (int f = 0; f < 32; ++f) { int fc = f << 9; lds[(tp | fc) ^ mt ^ mixF(fc)] = v[f]; } }
    __syncthreads();

    { int tp = ((t & 1) << 12) | (((t >> 1) & 1) << 13) | (((t >> 2) & 1) << 0)
             | (((t >> 3) & 1) << 9) | (((t >> 4) & 1) << 10) | (((t >> 5) & 1) << 11)
             | (((t >> 6) & 1) << 2) | (((t >> 7) & 1) << 3) | (((t >> 8) & 1) << 4);
      int mt = mixF(tp);
#pragma unroll
      for (int p = 0; p < 32; ++p) {
        int fc = ((p & 1) << 8) | (((p >> 1) & 1) << 1) | (((p >> 2) & 1) << 5)
               | (((p >> 3) & 1) << 6) | (((p >> 4) & 1) << 7);
        v[p] = lds[(tp | fc) ^ mt ^ mixF(fc)]; }
      if (lowry) { RYT_(csl, 1, 19); }
      CXI_((t >> 3) & 1, 1);
      RYT_(csl2, 16, 3); RYT_(csl2, 8, 4); RYT_(csl2, 4, 5);
      CXI_((t >> 6) & 1, 16); CX_(16, 8); CX_(8, 4); CX_(4, 2);
      int sb = (blk << 12) + t;
#pragma unroll
      for (int j = 0; j < 8; ++j)
        dst[sb + (j << 9)] = make_uint2(pk2(v[4*j], v[4*j+1]), pk2(v[4*j+2], v[4*j+3])); }
}

// ---------------- Pass L body: Q -> M (fp16) or std+abs (f32) ---------------
__device__ __forceinline__ void body_L(const uint2* __restrict__ src,
    float4* __restrict__ dstf, uint2* __restrict__ dsth,
    const float2* __restrict__ cs, int layer, bool fin, int blk, int t, float* lds)
{
    const float2* csl = cs + layer * 20;
    int H = blk & 63, b = blk >> 6;
    int Hp = (((H >> 3) & 7) << 6) | ((H & 7) << 9);
    float v[32];

    { int rb = (b << 6) | ((t >> 6) & 7);
      int lo = Hp + (t & 63);
#pragma unroll
      for (int i = 0; i < 8; ++i) {
        uint2 w = src[((rb | (i << 3)) << 12) + lo];
        float2 l2 = upk2(w.x), h2 = upk2(w.y);
        v[i*4+0] = l2.x; v[i*4+1] = l2.y; v[i*4+2] = h2.x; v[i*4+3] = h2.y;
      } }
    RYT_(csl, 1, 19); RYT_(csl, 4, 9); RYT_(csl, 8, 8); RYT_(csl, 16, 7);
    { int w1x = (t & 31) ^ (((t >> 5) & 1) << 4) ^ (((t >> 6) & 1) << 2)
              ^ (((t >> 7) & 1) << 3) ^ (((t >> 8) & 1) << 4);
#pragma unroll
      for (int m = 0; m < 32; ++m) lds[(t << 5) | (m ^ w1x)] = v[m]; }
    __syncthreads();

    { int tp = (t & 3) | (((t >> 2) & 1) << 7) | (((t >> 3) & 1) << 8)
             | (((t >> 4) & 1) << 9) | (((t >> 5) & 1) << 10) | (((t >> 6) & 1) << 5)
             | (((t >> 7) & 1) << 6) | (((t >> 8) & 1) << 11);
      int mt = mixL(tp);
#pragma unroll
      for (int f = 0; f < 32; ++f) {
        int fc = ((f & 1) << 12) | (((f >> 1) & 1) << 13) | (((f >> 2) & 1) << 2)
               | (((f >> 3) & 1) << 3) | (((f >> 4) & 1) << 4);
        v[f] = lds[(tp | fc) ^ mt ^ mixL(fc)]; }
      RYT_(csl, 2, 10); RYT_(csl, 1, 11);
      CXI_((t >> 1) & 1, 16); CX_(16, 8); CX_(8, 4); CX_(4, 2); CX_(2, 1);
#pragma unroll
      for (int f = 0; f < 32; ++f) {
        int fc = ((f & 1) << 12) | (((f >> 1) & 1) << 13) | (((f >> 2) & 1) << 2)
               | (((f >> 3) & 1) << 3) | (((f >> 4) & 1) << 4);
        lds[(tp | fc) ^ mt ^ mixL(fc)] = v[f]; } }
    __syncthreads();

    { int tp = (t & 31) | (((t >> 5) & 1) << 9) | (((t >> 6) & 1) << 8)
             | (((t >> 7) & 1) << 12) | (((t >> 8) & 1) << 13);
      int mt = mixL(tp);
#pragma unroll
      for (int f = 0; f < 32; ++f) {
        int fc = ((f & 1) << 10) | (((f >> 1) & 1) << 5) | (((f >> 2) & 1) << 6)
               | (((f >> 3) & 1) << 7) | (((f >> 4) & 1) << 11);
        v[f] = lds[(tp | fc) ^ mt ^ mixL(fc)]; }
      RYT_(csl, 16, 12); RYT_(csl, 8, 13); RYT_(csl, 4, 14); RYT_(csl, 2, 15); RYT_(csl, 1, 16);
      CXI_((t >> 7) & 1, 16); CX_(16, 8); CX_(8, 4); CX_(4, 2); CX_(2, 1);
#pragma unroll
      for (int f = 0; f < 32; ++f) {
        int fc = ((f & 1) << 10) | (((f >> 1) & 1) << 5) | (((f >> 2) & 1) << 6)
               | (((f >> 3) & 1) << 7) | (((f >> 4) & 1) << 11);
        lds[(tp | fc) ^ mt ^ mixL(fc)] = v[f]; } }
    __syncthreads();

    { int tp;
      if (!fin)
        tp = ((t & 1) << 2) | (((t >> 1) & 1) << 3) | (((t >> 2) & 1) << 4)
           | (((t >> 3) & 1) << 10) | (((t >> 4) & 1) << 5) | (((t >> 5) & 1) << 6)
           | (((t >> 6) & 1) << 1) | (((t >> 7) & 1) << 12) | (((t >> 8) & 1) << 13);
      else
        tp = ((t & 1) << 10) | (((t >> 1) & 1) << 5) | (((t >> 2) & 1) << 6)
           | (((t >> 3) & 1) << 12) | (((t >> 4) & 1) << 13) | (((t >> 5) & 1) << 2)
           | (((t >> 6) & 1) << 1) | (((t >> 7) & 1) << 3) | (((t >> 8) & 1) << 4);
      int mt = mixL(tp);
#pragma unroll
      for (int u = 0; u < 32; ++u) {
        int fc = ((u & 1) << 0) | (((u >> 1) & 1) << 8) | (((u >> 2) & 1) << 9)
               | (((u >> 3) & 1) << 7) | (((u >> 4) & 1) << 11);
        v[u] = lds[(tp | fc) ^ mt ^ mixL(fc)]; }
      RYT_(csl, 4, 17); RYT_(csl, 2, 18);
      { int e3 = fin ? (t & 1) : ((t >> 3) & 1);
        CXI_(e3, 4); }
      CX_(4, 2); CX_(2, 1);
      if (!fin) {
        int sb = (blk << 12) + (t & 7) + (((t >> 3) & 7) << 6)
               + (((t >> 7) & 3) << 9) + (((t >> 6) & 1) << 11);
#pragma unroll
        for (int g = 0; g < 8; ++g) {
          int bu = ((g >> 2) & 1) | (((g >> 1) & 1) << 1) | ((g & 1) << 2);
          dsth[sb + (g << 3)] = make_uint2(pk2(v[bu], v[bu | 8]), pk2(v[bu | 16], v[bu | 24]));
        }
      } else {
        int sb = (blk << 12) + ((t & 7) << 1) + (((t >> 3) & 7) << 6)
               + (((t >> 7) & 1) << 9) + (((t >> 8) & 1) << 10) + (((t >> 6) & 1) << 11);
#pragma unroll
        for (int g = 0; g < 8; ++g) {
          int bu = ((g & 1) << 2) | (((g >> 1) & 1) << 3) | (((g >> 2) & 1) << 4);
          dstf[sb + (g & 1) + (((g >> 1) & 1) << 4) + (((g >> 2) & 1) << 5)] =
            make_float4(fabsf(v[bu]), fabsf(v[bu | 1]), fabsf(v[bu | 2]), fabsf(v[bu | 3]));
        }
      } }
}

// ---------------- Region-structured persistent scheduler ----------------
// One ticket loop per pass, sequential; fast blocks fall through into the
// next pass while stragglers finish the current one (soft per-batch deps).
// tt = per-iteration OPAQUE copy of t: the empty volatile asm pins all
// t-derived address math inside its own region loop (no LICM hoist to
// function entry, no cross-region CSE) -> register demand stays ~ one body.
#define QREGION(P, CALLBODY) \
  for (;;) { \
    __syncthreads();                    /* protect stk + lds reuse */ \
    if (t == 0) stk = atomicAdd(&tickets[P], 1); \
    __syncthreads(); \
    int tk = __builtin_amdgcn_readfirstlane(stk); \
    if (tk >= 1024) break; \
    int b = tk >> 6; int blk = tk; (void)b; \
    int tt = t; asm volatile("" : "+v"(tt)); \
    if ((P) > 0) { \
      if (t == 0) { \
        int* f = done + ((P) - 1) * 16 + b; \
        long spins = 0; \
        while (__hip_atomic_load(f, __ATOMIC_RELAXED, __HIP_MEMORY_SCOPE_AGENT) < 64) { \
          __builtin_amdgcn_s_sleep(8); \
          if (++spins > (1L << 18)) break;   /* bounded: bug -> wrong, not hang */ \
        } \
        __threadfence();                /* acquire */ \
      } \
      __syncthreads(); \
    } \
    CALLBODY; \
    __syncthreads();                    /* drains vmcnt: stores in L2 */ \
    if ((P) < 6 && t == 0) { __threadfence(); atomicAdd(done + (P) * 16 + b, 1); } \
  }

__global__ __launch_bounds__(512, 2) void qsim(
    const float4* __restrict__ x, float4* __restrict__ outF,
    uint2* __restrict__ B0, uint2* __restrict__ B1,
    const float2* __restrict__ cs, int* __restrict__ ctrl)
{
    __shared__ float lds[16384];
    __shared__ int stk;
    int t = threadIdx.x;
    int* tickets = ctrl;      // [0..6] per-pass ticket counters
    int* done = ctrl + 8;     // done[p*16+b], p=0..5

    QREGION(0, body_R(x, B0, cs, blk, tt, lds));
    QREGION(1, body_A(B0, B1, cs, 0, false, blk, tt, lds));
    QREGION(2, body_F(B1, B0, cs, 0, false, blk, tt, lds));
    QREGION(3, body_L(B0, nullptr, B1, cs, 1, false, blk, tt, lds));
    QREGION(4, body_A(B1, B0, cs, 2, true, blk, tt, lds));
    QREGION(5, body_F(B0, B1, cs, 2, true, blk, tt, lds));
    QREGION(6, body_L(B1, outF, nullptr, cs, 3, true, blk, tt, lds));
}

extern "C" void kernel_launch(void* const* d_in, const int* in_sizes, int n_in,
                              void* d_out, int out_size, void* d_ws, size_t ws_size,
                              hipStream_t stream) {
    const float* x     = (const float*)d_in[0];   // (16, 2^20) f32, standard layout
    const float* theta = (const float*)d_in[1];   // (80,) f32
    float2* cs = (float2*)d_ws;                   // 80 (cos,sin) pairs @ +0
    int* ctrl  = (int*)((char*)d_ws + 1024);      // 7 tickets + 96 done flags
    uint2* B0  = (uint2*)((char*)d_ws + 4096);            // 32 MB fp16 state
    uint2* B1  = (uint2*)((char*)d_ws + 4096 + (32u<<20)); // 32 MB fp16 state
    float4* outF = (float4*)d_out;

    cs_zero_kernel<<<1, 128, 0, stream>>>(theta, cs, ctrl);
    qsim<<<512, 512, 0, stream>>>((const float4*)x, outF, B0, B1, cs, ctrl);
}

// Round 12
// 258.101 us; speedup vs baseline: 5.1222x; 2.6940x over previous
//
#include <hip/hip_runtime.h>
#include <hip/hip_fp16.h>
#include <math.h>

// Quantum circuit sim, 20 qubits, 4 layers, batch 16, purely-real f32 state.
// Element bit Ek <-> qubit q = 19-k. 7 fused passes, each pass = one kernel:
//   R : RY on E13..E0                       (layer 0)           std -> M
//   A : RY E19..E14(+E13..E6 if FULL) + CNOT chain (19,18)..(7,6)   M -> P
//   F : chain (6,5)..(1,0) [layer l] (+RY E5..E0 if LOWRY)
//       + RY E19..E13 + chain (19,18)..(14,13) [layer l+1]          P -> Q
//   L : RY E12..E0 + chain (13,12)..(1,0) (+abs if FIN)             Q -> M/std
// Schedule: R(0) A(0) F(0,1) L(1) A*(2) F*(2,3) L*(3).
// fp16 packed intermediates (uint2 = 4 halves at the old float4 index):
// halves HBM write traffic and keeps the 64MB ping-pong set L3-resident.
// VERIFIED 257.6 us (R5). Fusion/persistent-kernel variants (R8-R11) were
// measured slower for three distinct reasons (spill, LICM pressure,
// dependency convoying) — this 7-launch structure is the session's best.

__global__ void cs_kernel(const float* __restrict__ theta, float2* __restrict__ cs) {
    int i = threadIdx.x;
    if (i < 80) {
        float s, c;
        sincosf(theta[i] * 0.5f, &s, &c);
        cs[i] = make_float2(c, s);
    }
}

union H2U { __half2 h; unsigned u; };
__device__ __forceinline__ unsigned pk2(float a, float b) {
    H2U x; x.h = __float22half2_rn(make_float2(a, b)); return x.u;
}
__device__ __forceinline__ float2 upk2(unsigned u) {
    H2U x; x.u = u; return __half22float2(x.h);
}

// RY on fragment bit MASK with angle table TBL[Q]
#define RYT_(TBL, MASK, Q) { float2 _sc = (TBL)[(Q)]; float _c = _sc.x, _s = _sc.y; \
  _Pragma("unroll") for (int _m = 0; _m < 32; ++_m) if (!(_m & (MASK))) { \
    float _a = v[_m], _b = v[_m | (MASK)]; \
    v[_m] = _c*_a - _s*_b; v[_m | (MASK)] = _s*_a + _c*_b; } }

// CNOT: control mask CM, target mask TM, both in fragment
#define CX_(CM, TM) { _Pragma("unroll") for (int _m = 0; _m < 32; ++_m) \
  if ((_m & (CM)) && !(_m & (TM))) { float _t = v[_m]; v[_m] = v[_m|(TM)]; v[_m|(TM)] = _t; } }

// CNOT with control on a thread-index bit (COND), target mask TM in fragment
#define CXI_(COND, TM) { if (COND) { _Pragma("unroll") for (int _m = 0; _m < 32; ++_m) \
  if (!(_m & (TM))) { float _t = v[_m]; v[_m] = v[_m|(TM)]; v[_m|(TM)] = _t; } } }

__device__ __forceinline__ int mixR(int n) {
    return ((n >> 5) & 31) ^ ((n >> 10) & 1);
}
__device__ __forceinline__ int mixA(int n) {
    return ((n >> 5) & 31) ^ ((n >> 10) & 1) ^ (((n >> 11) & 1) << 3)
         ^ (((n >> 12) & 1) << 4) ^ (((n >> 13) & 1) << 4);
}
__device__ __forceinline__ int mixF(int n) {
    return ((n >> 5) & 31) ^ (((n >> 10) & 1) << 1) ^ (((n >> 11) & 1) << 2)
         ^ (((n >> 12) & 1) << 3) ^ (((n >> 13) & 1) << 4);
}
__device__ __forceinline__ int mixL(int n) {
    return ((n >> 5) & 31) ^ (((n >> 10) & 1) << 4) ^ (((n >> 11) & 1) << 2)
         ^ (((n >> 12) & 1) << 3) ^ (((n >> 13) & 1) << 4);
}

// ---------------- Pass R: std -> M, RY on E13..E0 (layer 0) ----------------
// n: [n0..n4]=(E0,E1,E10,E11,E12) [n5..n10]=(E2..E7) [n11..n13]=(E8,E9,E13)
__global__ __launch_bounds__(512, 4) void pass_R(
    const float4* __restrict__ src, uint2* __restrict__ dst,
    const float2* __restrict__ cs)
{
    __shared__ float lds[16384];
    const float2* csl = cs;                       // layer 0
    int t = threadIdx.x, blk = blockIdx.x;
    int H = blk & 63, b = blk >> 6;
    int base = (b << 18) + (H << 12);
    float v[32];

    // load (standard, f32): t[5:0]=E2..E7, t[7:6]=E8,E9, t[8]=E13; i=(E10,E11,E12)
#pragma unroll
    for (int i = 0; i < 8; ++i) {
        float4 w = src[base + (i << 8) + (((t >> 6) & 3) << 6) + (((t >> 8) & 1) << 11) + (t & 63)];
        v[i*4+0] = w.x; v[i*4+1] = w.y; v[i*4+2] = w.z; v[i*4+3] = w.w;
    }
    // r1: m=(E0,E1,E10,E11,E12) -> RY q19,q18,q9,q8,q7
    RYT_(csl, 1, 19); RYT_(csl, 2, 18); RYT_(csl, 4, 9); RYT_(csl, 8, 8); RYT_(csl, 16, 7);
    { int w1x = (t & 31) ^ ((t >> 5) & 1);
#pragma unroll
      for (int m = 0; m < 32; ++m) lds[(t << 5) | (m ^ w1x)] = v[m]; }
    __syncthreads();

    // r2: frag=(E2,E3,E4,E5,E6) -> RY q17,q16,q15,q14,q13
    { int tp = (t & 31) | (((t >> 5) & 1) << 10) | (((t >> 6) & 7) << 11);
      int mt = mixR(tp);
#pragma unroll
      for (int f = 0; f < 32; ++f) { int fc = f << 5; v[f] = lds[(tp | fc) ^ mt ^ mixR(fc)]; }
      RYT_(csl, 1, 17); RYT_(csl, 2, 16); RYT_(csl, 4, 15); RYT_(csl, 8, 14); RYT_(csl, 16, 13);
#pragma unroll
      for (int f = 0; f < 32; ++f) { int fc = f << 5; lds[(tp | fc) ^ mt ^ mixR(fc)] = v[f]; } }
    __syncthreads();

    // r3: p=(E6,E7,E8,E9,E13) -> RY q12(2),q11(4),q10(8),q6(16)
    { int tp = ((t & 1) << 2) | (((t >> 1) & 1) << 3) | (((t >> 2) & 1) << 4)
             | (((t >> 3) & 1) << 5) | (((t >> 4) & 1) << 1) | (((t >> 5) & 1) << 0)
             | (((t >> 6) & 7) << 6);
      int mt = mixR(tp);
#pragma unroll
      for (int p = 0; p < 32; ++p) { int fc = p << 9; v[p] = lds[(tp | fc) ^ mt ^ mixR(fc)]; }
      RYT_(csl, 2, 12); RYT_(csl, 4, 11); RYT_(csl, 8, 10); RYT_(csl, 16, 6);
      // store -> M (fp16): slot k of idx = k-th float of old float4
      int sb = base + (((t >> 6) & 7) << 6) + (t & 63);
#pragma unroll
      for (int j = 0; j < 8; ++j)
        dst[sb + (j << 9)] = make_uint2(pk2(v[4*j], v[4*j+1]), pk2(v[4*j+2], v[4*j+3])); }
}

// ---------------- Pass A: M -> P ----------------
// n: [n0..n4]=(E6,E7,E17,E18,E19) [n5..n10]=(E10,E11,E12,E14,E15,E16)
//    [n11..n13]=(E8,E9,E13)
template <bool FULL>
__global__ __launch_bounds__(512, 4) void pass_A(
    const uint2* __restrict__ src, uint2* __restrict__ dst,
    const float2* __restrict__ cs, int layer)
{
    __shared__ float lds[16384];
    const float2* csl = cs + layer * 20;
    int t = threadIdx.x, blk = blockIdx.x;
    int G = blk & 63, b = blk >> 6;
    int Gperm = ((G >> 2) & 1) | (((G >> 1) & 1) << 1) | ((G & 1) << 2) | (((G >> 3) & 7) << 3);
    float v[32];

    // load from M (fp16)
    { int lb = (b << 18) + (((t >> 6) & 7) << 9) + (Gperm << 3) + (t & 7);
      int rg = ((t >> 3) & 7) << 12;
#pragma unroll
      for (int i = 0; i < 8; ++i) {
        uint2 w = src[lb + ((i << 3) << 12) + rg];
        float2 lo = upk2(w.x), hi = upk2(w.y);
        v[i*4+0] = lo.x; v[i*4+1] = lo.y; v[i*4+2] = hi.x; v[i*4+3] = hi.y;
      } }
    // r1: m=(E6,E7,E17,E18,E19): RY q0(16),q1(8),q2(4); FULL: q12(2),q13(1)
    RYT_(csl, 16, 0); RYT_(csl, 8, 1); RYT_(csl, 4, 2);
    if (FULL) { RYT_(csl, 2, 12); RYT_(csl, 1, 13); }
    { int w1x = (t & 31) ^ ((t >> 5) & 1) ^ (((t >> 6) & 1) << 3)
              ^ (((t >> 7) & 1) << 4) ^ (((t >> 8) & 1) << 4);
#pragma unroll
      for (int m = 0; m < 32; ++m) lds[(t << 5) | (m ^ w1x)] = v[m]; }
    __syncthreads();

    // r2: frag=(E15,E16,E17,E18,E19): RY q4(1),q3(2); links (19,18)..(16,15)
    { int tp = (t & 3) | (((t >> 2) & 1) << 7) | (((t >> 3) & 1) << 11)
             | (((t >> 4) & 1) << 12) | (((t >> 5) & 1) << 13) | (((t >> 6) & 1) << 5)
             | (((t >> 7) & 1) << 6) | (((t >> 8) & 1) << 8);
      int mt = mixA(tp);
#pragma unroll
      for (int f = 0; f < 32; ++f) {
        int fc = ((f & 1) << 9) | (((f >> 1) & 1) << 10) | (((f >> 2) & 1) << 2)
               | (((f >> 3) & 1) << 3) | (((f >> 4) & 1) << 4);
        v[f] = lds[(tp | fc) ^ mt ^ mixA(fc)]; }
      RYT_(csl, 1, 4); RYT_(csl, 2, 3);
      CX_(16, 8); CX_(8, 4); CX_(4, 2); CX_(2, 1);
#pragma unroll
      for (int f = 0; f < 32; ++f) {
        int fc = ((f & 1) << 9) | (((f >> 1) & 1) << 10) | (((f >> 2) & 1) << 2)
               | (((f >> 3) & 1) << 3) | (((f >> 4) & 1) << 4);
        lds[(tp | fc) ^ mt ^ mixA(fc)] = v[f]; } }
    __syncthreads();

    // r3: frag=(E10,E11,E12,E13,E14): RY q5(16); FULL q6(8),q7(4),q8(2),q9(1)
    //     links (15,14)[idx],(14,13),(13,12),(12,11),(11,10)
    { int tp = (t & 31) | (((t >> 5) & 1) << 9) | (((t >> 6) & 1) << 10)
             | (((t >> 7) & 1) << 11) | (((t >> 8) & 1) << 12);
      int mt = mixA(tp);
#pragma unroll
      for (int f = 0; f < 32; ++f) {
        int fc = ((f & 1) << 5) | (((f >> 1) & 1) << 6) | (((f >> 2) & 1) << 7)
               | (((f >> 3) & 1) << 13) | (((f >> 4) & 1) << 8);
        v[f] = lds[(tp | fc) ^ mt ^ mixA(fc)]; }
      RYT_(csl, 16, 5);
      if (FULL) { RYT_(csl, 8, 6); RYT_(csl, 4, 7); RYT_(csl, 2, 8); RYT_(csl, 1, 9); }
      CXI_((t >> 5) & 1, 16); CX_(16, 8); CX_(8, 4); CX_(4, 2); CX_(2, 1);
#pragma unroll
      for (int f = 0; f < 32; ++f) {
        int fc = ((f & 1) << 5) | (((f >> 1) & 1) << 6) | (((f >> 2) & 1) << 7)
               | (((f >> 3) & 1) << 13) | (((f >> 4) & 1) << 8);
        lds[(tp | fc) ^ mt ^ mixA(fc)] = v[f]; } }
    __syncthreads();

    // r4: p=(E6,E13,E7,E8,E9): FULL RY q10(16),q11(8);
    //     links (10,9)[idx t4[6]],(9,8):16->8,(8,7):8->4,(7,6):4->1
    { int tp = ((t & 1) << 8) | (((t >> 1) & 1) << 9) | (((t >> 2) & 1) << 10)
             | (((t >> 3) & 1) << 6) | (((t >> 4) & 1) << 7) | (((t >> 5) & 1) << 2)
             | (((t >> 6) & 1) << 5) | (((t >> 7) & 1) << 3) | (((t >> 8) & 1) << 4);
      int mt = mixA(tp);
#pragma unroll
      for (int p = 0; p < 32; ++p) {
        int fc = ((p & 1) << 0) | (((p >> 1) & 1) << 13) | (((p >> 2) & 1) << 1)
               | (((p >> 3) & 1) << 11) | (((p >> 4) & 1) << 12);
        v[p] = lds[(tp | fc) ^ mt ^ mixA(fc)]; }
      if (FULL) { RYT_(csl, 16, 10); RYT_(csl, 8, 11); }
      CXI_((t >> 6) & 1, 16); CX_(16, 8); CX_(8, 4); CX_(4, 1);
      // store -> P (fp16): f4-slot index = b<<18 | G<<12 | j<<9 | t
      int sb = (b << 18) + (G << 12) + t;
#pragma unroll
      for (int j = 0; j < 8; ++j)
        dst[sb + (j << 9)] = make_uint2(pk2(v[4*j], v[4*j+1]), pk2(v[4*j+2], v[4*j+3])); }
}

// ---------------- Pass F: P -> Q ----------------
// n: [n0..n4]=(E6,E13,E17,E18,E19) [n5..n10]=(E14,E15,E16,E0,E1,E2)
//    [n11..n13]=(E3,E4,E5)
template <bool LOWRY>
__global__ __launch_bounds__(512, 4) void pass_F(
    const uint2* __restrict__ src, uint2* __restrict__ dst,
    const float2* __restrict__ cs, int layer)
{
    __shared__ float lds[16384];
    const float2* csl  = cs + layer * 20;         // layer l (low chain / low RY)
    const float2* csl2 = cs + (layer + 1) * 20;   // layer l+1 (hi RY + hi chain)
    int t = threadIdx.x, blk = blockIdx.x;
    int W = blk & 63, b = blk >> 6;
    int Wp = (((W >> 4) & 1) << 3) | (((W >> 5) & 1) << 4) | (((W >> 3) & 1) << 6)
           | ((W & 1) << 9) | (((W >> 1) & 1) << 10) | (((W >> 2) & 1) << 11);
    float v[32];

    // load from P (fp16)
    { int lb = (((b << 6) | ((t >> 3) & 63)) << 12) + (t & 7) + Wp;
#pragma unroll
      for (int i = 0; i < 8; ++i) {
        uint2 w = src[lb + ((i & 1) << 5) + (((i >> 1) & 1) << 7) + (((i >> 2) & 1) << 8)];
        float2 lo = upk2(w.x), hi = upk2(w.y);
        v[i*4+0] = lo.x; v[i*4+1] = lo.y; v[i*4+2] = hi.x; v[i*4+3] = hi.y;
      } }
    // r1: m=(E6,E13,E17,E18,E19): RY+1 q0(16),q1(8),q2(4),q6(2); links+1 (19,18),(18,17)
    RYT_(csl2, 16, 0); RYT_(csl2, 8, 1); RYT_(csl2, 4, 2); RYT_(csl2, 2, 6);
    CX_(16, 8); CX_(8, 4);
    { int w1x = (t & 31) ^ (((t >> 5) & 1) << 1) ^ (((t >> 6) & 1) << 2)
              ^ (((t >> 7) & 1) << 3) ^ (((t >> 8) & 1) << 4);
#pragma unroll
      for (int m = 0; m < 32; ++m) lds[(t << 5) | (m ^ w1x)] = v[m]; }
    __syncthreads();

    // r2: frag=(E1,E2,E3,E4,E5): [LOWRY q14(16)..q18(1)]; links_l (6,5)[idx]..(2,1)
    { int tp = (t & 31) | (((t >> 5) & 1) << 8) | (((t >> 6) & 1) << 5)
             | (((t >> 7) & 1) << 6) | (((t >> 8) & 1) << 7);
      int mt = mixF(tp);
#pragma unroll
      for (int f = 0; f < 32; ++f) { int fc = f << 9; v[f] = lds[(tp | fc) ^ mt ^ mixF(fc)]; }
      if (LOWRY) { RYT_(csl, 16, 14); RYT_(csl, 8, 15); RYT_(csl, 4, 16); RYT_(csl, 2, 17); RYT_(csl, 1, 18); }
      CXI_(t & 1, 16); CX_(16, 8); CX_(8, 4); CX_(4, 2); CX_(2, 1);
#pragma unroll
      for (int f = 0; f < 32; ++f) { int fc = f << 9; lds[(tp | fc) ^ mt ^ mixF(fc)] = v[f]; } }
    __syncthreads();

    // r3: p=(E0,E13,E14,E15,E16): [LOWRY q19(1)]; link_l (1,0)[idx t3[3]];
    //     RY+1 q3(16),q4(8),q5(4); links+1 (17,16)[idx t3[6]],(16,15),(15,14),(14,13)
    { int tp = ((t & 1) << 12) | (((t >> 1) & 1) << 13) | (((t >> 2) & 1) << 0)
             | (((t >> 3) & 1) << 9) | (((t >> 4) & 1) << 10) | (((t >> 5) & 1) << 11)
             | (((t >> 6) & 1) << 2) | (((t >> 7) & 1) << 3) | (((t >> 8) & 1) << 4);
      int mt = mixF(tp);
#pragma unroll
      for (int p = 0; p < 32; ++p) {
        int fc = ((p & 1) << 8) | (((p >> 1) & 1) << 1) | (((p >> 2) & 1) << 5)
               | (((p >> 3) & 1) << 6) | (((p >> 4) & 1) << 7);
        v[p] = lds[(tp | fc) ^ mt ^ mixF(fc)]; }
      if (LOWRY) { RYT_(csl, 1, 19); }
      CXI_((t >> 3) & 1, 1);
      RYT_(csl2, 16, 3); RYT_(csl2, 8, 4); RYT_(csl2, 4, 5);
      CXI_((t >> 6) & 1, 16); CX_(16, 8); CX_(8, 4); CX_(4, 2);
      // store -> Q (fp16): f4-slot index = blk<<12 | j<<9 | t
      int sb = (blk << 12) + t;
#pragma unroll
      for (int j = 0; j < 8; ++j)
        dst[sb + (j << 9)] = make_uint2(pk2(v[4*j], v[4*j+1]), pk2(v[4*j+2], v[4*j+3])); }
}

// ---------------- Pass L: Q -> M (mid, fp16) or std+abs (fin, f32) ----------------
// n: [n0..n4]=(E0,E13,E10,E11,E12) [n5..n10]=(E4,E5,E6,E1,E2,E3)
//    [n11..n13]=(E7,E8,E9)
template <bool FIN>
__global__ __launch_bounds__(512, 4) void pass_L(
    const uint2* __restrict__ src, float4* __restrict__ dstf,
    uint2* __restrict__ dsth, const float2* __restrict__ cs, int layer)
{
    __shared__ float lds[16384];
    const float2* csl = cs + layer * 20;
    int t = threadIdx.x, blk = blockIdx.x;
    int H = blk & 63, b = blk >> 6;
    int Hp = (((H >> 3) & 7) << 6) | ((H & 7) << 9);
    float v[32];

    // load from Q (fp16)
    { int rb = (b << 6) | ((t >> 6) & 7);
      int lo = Hp + (t & 63);
#pragma unroll
      for (int i = 0; i < 8; ++i) {
        uint2 w = src[((rb | (i << 3)) << 12) + lo];
        float2 l2 = upk2(w.x), h2 = upk2(w.y);
        v[i*4+0] = l2.x; v[i*4+1] = l2.y; v[i*4+2] = h2.x; v[i*4+3] = h2.y;
      } }
    // r1: m=(E0,E13,E10,E11,E12): RY q19(1),q9(4),q8(8),q7(16)
    RYT_(csl, 1, 19); RYT_(csl, 4, 9); RYT_(csl, 8, 8); RYT_(csl, 16, 7);
    { int w1x = (t & 31) ^ (((t >> 5) & 1) << 4) ^ (((t >> 6) & 1) << 2)
              ^ (((t >> 7) & 1) << 3) ^ (((t >> 8) & 1) << 4);
#pragma unroll
      for (int m = 0; m < 32; ++m) lds[(t << 5) | (m ^ w1x)] = v[m]; }
    __syncthreads();

    // r2: frag=(E8,E9,E10,E11,E12): RY q10(2),q11(1);
    //     links (13,12)[idx t2[1]],(12,11),(11,10),(10,9),(9,8)
    { int tp = (t & 3) | (((t >> 2) & 1) << 7) | (((t >> 3) & 1) << 8)
             | (((t >> 4) & 1) << 9) | (((t >> 5) & 1) << 10) | (((t >> 6) & 1) << 5)
             | (((t >> 7) & 1) << 6) | (((t >> 8) & 1) << 11);
      int mt = mixL(tp);
#pragma unroll
      for (int f = 0; f < 32; ++f) {
        int fc = ((f & 1) << 12) | (((f >> 1) & 1) << 13) | (((f >> 2) & 1) << 2)
               | (((f >> 3) & 1) << 3) | (((f >> 4) & 1) << 4);
        v[f] = lds[(tp | fc) ^ mt ^ mixL(fc)]; }
      RYT_(csl, 2, 10); RYT_(csl, 1, 11);
      CXI_((t >> 1) & 1, 16); CX_(16, 8); CX_(8, 4); CX_(4, 2); CX_(2, 1);
#pragma unroll
      for (int f = 0; f < 32; ++f) {
        int fc = ((f & 1) << 12) | (((f >> 1) & 1) << 13) | (((f >> 2) & 1) << 2)
               | (((f >> 3) & 1) << 3) | (((f >> 4) & 1) << 4);
        lds[(tp | fc) ^ mt ^ mixL(fc)] = v[f]; } }
    __syncthreads();

    // r3: frag=(E3,E4,E5,E6,E7): RY q12(16),q13(8),q14(4),q15(2),q16(1);
    //     links (8,7)[idx t3[7]],(7,6),(6,5),(5,4),(4,3)
    { int tp = (t & 31) | (((t >> 5) & 1) << 9) | (((t >> 6) & 1) << 8)
             | (((t >> 7) & 1) << 12) | (((t >> 8) & 1) << 13);
      int mt = mixL(tp);
#pragma unroll
      for (int f = 0; f < 32; ++f) {
        int fc = ((f & 1) << 10) | (((f >> 1) & 1) << 5) | (((f >> 2) & 1) << 6)
               | (((f >> 3) & 1) << 7) | (((f >> 4) & 1) << 11);
        v[f] = lds[(tp | fc) ^ mt ^ mixL(fc)]; }
      RYT_(csl, 16, 12); RYT_(csl, 8, 13); RYT_(csl, 4, 14); RYT_(csl, 2, 15); RYT_(csl, 1, 16);
      CXI_((t >> 7) & 1, 16); CX_(16, 8); CX_(8, 4); CX_(4, 2); CX_(2, 1);
#pragma unroll
      for (int f = 0; f < 32; ++f) {
        int fc = ((f & 1) << 10) | (((f >> 1) & 1) << 5) | (((f >> 2) & 1) << 6)
               | (((f >> 3) & 1) << 7) | (((f >> 4) & 1) << 11);
        lds[(tp | fc) ^ mt ^ mixL(fc)] = v[f]; } }
    __syncthreads();

    // r4: u=(E0,E1,E2,E6,E7): RY q17(4),q18(2); links (3,2)[idx],(2,1),(1,0)
    { int tp;
      if (!FIN)
        tp = ((t & 1) << 2) | (((t >> 1) & 1) << 3) | (((t >> 2) & 1) << 4)
           | (((t >> 3) & 1) << 10) | (((t >> 4) & 1) << 5) | (((t >> 5) & 1) << 6)
           | (((t >> 6) & 1) << 1) | (((t >> 7) & 1) << 12) | (((t >> 8) & 1) << 13);
      else
        tp = ((t & 1) << 10) | (((t >> 1) & 1) << 5) | (((t >> 2) & 1) << 6)
           | (((t >> 3) & 1) << 12) | (((t >> 4) & 1) << 13) | (((t >> 5) & 1) << 2)
           | (((t >> 6) & 1) << 1) | (((t >> 7) & 1) << 3) | (((t >> 8) & 1) << 4);
      int mt = mixL(tp);
#pragma unroll
      for (int u = 0; u < 32; ++u) {
        int fc = ((u & 1) << 0) | (((u >> 1) & 1) << 8) | (((u >> 2) & 1) << 9)
               | (((u >> 3) & 1) << 7) | (((u >> 4) & 1) << 11);
        v[u] = lds[(tp | fc) ^ mt ^ mixL(fc)]; }
      RYT_(csl, 4, 17); RYT_(csl, 2, 18);
      { int e3 = FIN ? (t & 1) : ((t >> 3) & 1);
        CXI_(e3, 4); }
      CX_(4, 2); CX_(2, 1);
      if (!FIN) {
        // store -> M (fp16)
        int sb = (blk << 12) + (t & 7) + (((t >> 3) & 7) << 6)
               + (((t >> 7) & 3) << 9) + (((t >> 6) & 1) << 11);
#pragma unroll
        for (int g = 0; g < 8; ++g) {
          int bu = ((g >> 2) & 1) | (((g >> 1) & 1) << 1) | ((g & 1) << 2);
          dsth[sb + (g << 3)] = make_uint2(pk2(v[bu], v[bu | 8]), pk2(v[bu | 16], v[bu | 24]));
        }
      } else {
        // store -> standard f32, with abs
        int sb = (blk << 12) + ((t & 7) << 1) + (((t >> 3) & 7) << 6)
               + (((t >> 7) & 1) << 9) + (((t >> 8) & 1) << 10) + (((t >> 6) & 1) << 11);
#pragma unroll
        for (int g = 0; g < 8; ++g) {
          int bu = ((g & 1) << 2) | (((g >> 1) & 1) << 3) | (((g >> 2) & 1) << 4);
          dstf[sb + (g & 1) + (((g >> 1) & 1) << 4) + (((g >> 2) & 1) << 5)] =
            make_float4(fabsf(v[bu]), fabsf(v[bu | 1]), fabsf(v[bu | 2]), fabsf(v[bu | 3]));
        }
      } }
}

extern "C" void kernel_launch(void* const* d_in, const int* in_sizes, int n_in,
                              void* d_out, int out_size, void* d_ws, size_t ws_size,
                              hipStream_t stream) {
    const float* x     = (const float*)d_in[0];   // (16, 2^20) f32, standard layout
    const float* theta = (const float*)d_in[1];   // (80,) f32
    float2* cs = (float2*)d_ws;                   // 80 (cos,sin) pairs
    uint2* wsH = (uint2*)((char*)d_ws + 4096);    // 32 MB fp16 scratch state
    uint2* outH = (uint2*)d_out;                  // out buffer doubles as fp16 scratch
    float4* outF = (float4*)d_out;                // final f32 output view

    cs_kernel<<<1, 128, 0, stream>>>(theta, cs);

    dim3 grid(1024), block(512);
    pass_R<<<grid, block, 0, stream>>>((const float4*)x, outH, cs);              // L0 lo-RY
    pass_A<false><<<grid, block, 0, stream>>>(outH, wsH, cs, 0);                 // L0 hi
    pass_F<false><<<grid, block, 0, stream>>>(wsH, outH, cs, 0);                 // L0 lo-chain + L1 hi
    pass_L<false><<<grid, block, 0, stream>>>(outH, nullptr, wsH, cs, 1);        // L1 lo
    pass_A<true><<<grid, block, 0, stream>>>(wsH, outH, cs, 2);                  // L2 hi (full RY)
    pass_F<true><<<grid, block, 0, stream>>>(outH, wsH, cs, 2);                  // L2 lo + L3 hi
    pass_L<true><<<grid, block, 0, stream>>>(wsH, outF, nullptr, cs, 3);         // L3 lo + abs
}